// Round 16
// baseline (93.494 us; speedup 1.0000x reference)
//
#include <hip/hip_runtime.h>
#include <cstdint>
#include <cstddef>

#define DZc   128
#define Lc    256
#define Hc    4
#define DCc   32
#define DHCc  128
#define NPOSc (Lc * Lc)

typedef __attribute__((ext_vector_type(8))) short bf16x8;
typedef __attribute__((ext_vector_type(4))) short bf16x4;
typedef __attribute__((ext_vector_type(4))) float f32x4;

static __device__ __forceinline__ unsigned short f2bf(float f) {
  unsigned u = __float_as_uint(f);
  u += 0x7FFFu + ((u >> 16) & 1u);     // round-to-nearest-even
  return (unsigned short)(u >> 16);
}
static __device__ __forceinline__ float bf2f(unsigned short h) {
  return __uint_as_float(((unsigned)h) << 16);
}
static __device__ __forceinline__ float sigmoidf_(float x) {
  return 1.0f / (1.0f + __expf(-x));
}
// HW packed f32->bf16 (RNE, bit-identical to f2bf): 1 instr instead of ~8.
static __device__ __forceinline__ unsigned cvtpk(float lo, float hi) {
  unsigned r;
  asm("v_cvt_pk_bf16_f32 %0, %1, %2" : "=v"(r) : "v"(lo), "v"(hi));
  return r;
}

// ---------------------------------------------------------------------------
// prep: weights fp32 [k][j] -> bf16 transposed [j][k]; q-scale folded into wq.
// slot 0..3 = wq,wk,wv,wg ; slot 4 = w2 (-> w2T[c][k]).
// ---------------------------------------------------------------------------
__global__ __launch_bounds__(256) void prep_weights(
    const float* __restrict__ wq, const float* __restrict__ wk,
    const float* __restrict__ wv, const float* __restrict__ wg,
    const float* __restrict__ w2, unsigned short* __restrict__ wT)
{
  const int b = blockIdx.x;  // 0..4
  const int t = threadIdx.x;
  const float* src = (b == 0) ? wq : (b == 1) ? wk : (b == 2) ? wv : (b == 3) ? wg : w2;
  unsigned short* dst = wT + (size_t)b * (DZc * DHCc);
  const float scale = (b == 0) ? 0.17677669529663687f : 1.0f;  // sqrt(1/32)
  for (int p = 0; p < 64; ++p) {
    const int idx = p * 256 + t;             // 16384 elements
    const int kk = idx >> 7, j = idx & 127;  // src[kk][j]
    dst[j * 128 + kk] = f2bf(src[idx] * scale);
  }
}

// ---------------------------------------------------------------------------
// FUSED kernel, R16: identical to passing R15 EXCEPT the occupancy pin.
//   R15 lesson: launch_bounds' 2nd arg is only a MIN waves/EU -- the
//   allocator still targeted 8 waves/EU -> VGPR 64 -> spills (56/95 MB).
//   amdgpu_waves_per_eu(4,4) pins BOTH bounds -> VGPR budget 128.
// ---------------------------------------------------------------------------
__global__ __launch_bounds__(1024)
__attribute__((amdgpu_waves_per_eu(4, 4)))
void fused_ln_proj_attn(
    const float* __restrict__ z, const float* __restrict__ lnw, const float* __restrict__ lnb,
    const unsigned short* __restrict__ wT,
    const float* __restrict__ bq, const float* __restrict__ bk,
    const float* __restrict__ bv, const float* __restrict__ bg,
    unsigned short* __restrict__ og_ws)
{
  __shared__ unsigned short zkl[Lc * DZc];     // 64 KB: zn, later K [j][128ch]
  __shared__ unsigned short vtl[DHCc * Lc];    // 64 KB: V^T [ch][ii]
  __shared__ unsigned short pll[16][16 * 64];  // 32 KB: per-wave P quarter

  const int t  = threadIdx.x;
  const int n  = blockIdx.x;
  const int w16 = t >> 6;
  const int l  = t & 63;
  const int lr = l & 15;
  const int lg = l >> 4;
  const int h  = w16 & 3;        // head for q/g/attention
  const int iq = w16 >> 2;       // query-row quarter for q/g/attention

  char* zkb = reinterpret_cast<char*>(zkl);
  char* vtb = reinterpret_cast<char*>(vtl);
  char* plb = reinterpret_cast<char*>(&pll[w16][0]);

  // ---- Phase A: LN (in-register stats, 16-lane shfl tree), single pass ----
  {
    const int pq = t >> 4;          // 0..63 pos-quad
    const int cg = t & 15;          // 0..15 channel group (8 ch)
    const int gp = n * 256 + pq * 4;
    const int cbase = cg * 8;

    float4 zr[8];
    #pragma unroll
    for (int cc = 0; cc < 8; ++cc)
      zr[cc] = *reinterpret_cast<const float4*>(&z[(size_t)(cbase + cc) * NPOSc + gp]);

    float s[4] = {0.f, 0.f, 0.f, 0.f}, s2[4] = {0.f, 0.f, 0.f, 0.f};
    #pragma unroll
    for (int cc = 0; cc < 8; ++cc) {
      s[0] += zr[cc].x; s2[0] += zr[cc].x * zr[cc].x;
      s[1] += zr[cc].y; s2[1] += zr[cc].y * zr[cc].y;
      s[2] += zr[cc].z; s2[2] += zr[cc].z * zr[cc].z;
      s[3] += zr[cc].w; s2[3] += zr[cc].w * zr[cc].w;
    }
    #pragma unroll
    for (int m = 1; m <= 8; m <<= 1) {
      #pragma unroll
      for (int e = 0; e < 4; ++e) {
        s[e]  += __shfl_xor(s[e],  m);
        s2[e] += __shfl_xor(s2[e], m);
      }
    }
    float mu[4], rs[4];
    #pragma unroll
    for (int e = 0; e < 4; ++e) {
      mu[e] = s[e] * (1.0f / DZc);
      const float var = s2[e] * (1.0f / DZc) - mu[e] * mu[e];
      rs[e] = rsqrtf(var + 1e-5f);
    }
    float lw[8], lb[8];
    #pragma unroll
    for (int q4 = 0; q4 < 2; ++q4) {
      const float4 a = *reinterpret_cast<const float4*>(&lnw[cbase + q4 * 4]);
      const float4 b = *reinterpret_cast<const float4*>(&lnb[cbase + q4 * 4]);
      lw[q4 * 4 + 0] = a.x; lw[q4 * 4 + 1] = a.y; lw[q4 * 4 + 2] = a.z; lw[q4 * 4 + 3] = a.w;
      lb[q4 * 4 + 0] = b.x; lb[q4 * 4 + 1] = b.y; lb[q4 * 4 + 2] = b.z; lb[q4 * 4 + 3] = b.w;
    }
    #pragma unroll
    for (int e = 0; e < 4; ++e) {
      const int i = pq * 4 + e;
      float zn[8];
      #pragma unroll
      for (int cc = 0; cc < 8; ++cc) {
        const float zc = (e == 0) ? zr[cc].x : (e == 1) ? zr[cc].y
                       : (e == 2) ? zr[cc].z : zr[cc].w;
        zn[cc] = (zc - mu[e]) * rs[e] * lw[cc] + lb[cc];
      }
      uint4 pw;
      pw.x = cvtpk(zn[0], zn[1]); pw.y = cvtpk(zn[2], zn[3]);
      pw.z = cvtpk(zn[4], zn[5]); pw.w = cvtpk(zn[6], zn[7]);
      int byte = i * 256 + cbase * 2;
      byte ^= ((i & 15) << 4);
      *reinterpret_cast<uint4*>(zkb + byte) = pw;
    }
  }
  __syncthreads();

  const unsigned short* wqT = wT;
  const unsigned short* wkT = wT + 1 * (DZc * DHCc);
  const unsigned short* wvT = wT + 2 * (DZc * DHCc);
  const unsigned short* wgT = wT + 3 * (DZc * DHCc);

  // ---- Phase B1: q -> qfrag[4] regs (attn B-frag layout) ----
  bf16x8 qfrag[4];
  {
    bf16x8 bfq[2][4];
    float4 qb4[2];
    #pragma unroll
    for (int jt = 0; jt < 2; ++jt) {
      #pragma unroll
      for (int kt = 0; kt < 4; ++kt)
        bfq[jt][kt] = *reinterpret_cast<const bf16x8*>(
            &wqT[(size_t)(h * 32 + jt * 16 + lr) * 128 + kt * 32 + lg * 8]);
      qb4[jt] = *reinterpret_cast<const float4*>(&bq[h * 32 + jt * 16 + lg * 4]);
      qb4[jt].x *= 0.17677669529663687f; qb4[jt].y *= 0.17677669529663687f;
      qb4[jt].z *= 0.17677669529663687f; qb4[jt].w *= 0.17677669529663687f;
    }
    #pragma unroll
    for (int it = 0; it < 4; ++it) {
      bf16x8 af[4];
      #pragma unroll
      for (int kt = 0; kt < 4; ++kt) {
        const int i = iq * 64 + it * 16 + lr;
        int byte = i * 256 + (kt * 64 + lg * 16);
        byte ^= ((i & 15) << 4);
        af[kt] = *reinterpret_cast<const bf16x8*>(zkb + byte);
      }
      f32x4 qa[2];
      qa[0] = (f32x4){0.f, 0.f, 0.f, 0.f};
      qa[1] = (f32x4){0.f, 0.f, 0.f, 0.f};
      #pragma unroll
      for (int kt = 0; kt < 4; ++kt)
        #pragma unroll
        for (int jt = 0; jt < 2; ++jt)
          qa[jt] = __builtin_amdgcn_mfma_f32_16x16x32_bf16(bfq[jt][kt], af[kt], qa[jt], 0, 0, 0);
      // srcw[jt][w]: ch = h*32 + jt*16 + lg*4 + 2w+{0,1}, pos = lr
      unsigned srcw0[2], srcw1[2];
      srcw0[0] = cvtpk(qa[0][0] + qb4[0].x, qa[0][1] + qb4[0].y);
      srcw0[1] = cvtpk(qa[0][2] + qb4[0].z, qa[0][3] + qb4[0].w);
      srcw1[0] = cvtpk(qa[1][0] + qb4[1].x, qa[1][1] + qb4[1].y);
      srcw1[1] = cvtpk(qa[1][2] + qb4[1].z, qa[1][3] + qb4[1].w);
      // shuffle to qfrag: lane wants row lr, ch octet lg*8 (quad 2lg, 2lg+1)
      unsigned qw[4];
      #pragma unroll
      for (int i4 = 0; i4 < 4; ++i4) {
        const int quad = lg * 2 + (i4 >> 1);
        const int srcl = (quad & 3) * 16 + lr;
        const unsigned a = (unsigned)__shfl((int)srcw0[i4 & 1], srcl);
        const unsigned b = (unsigned)__shfl((int)srcw1[i4 & 1], srcl);
        qw[i4] = (lg >= 2) ? b : a;   // jt_src = quad>>2 == (lg>=2)
      }
      uint4 qv; qv.x = qw[0]; qv.y = qw[1]; qv.z = qw[2]; qv.w = qw[3];
      qfrag[it] = *reinterpret_cast<const bf16x8*>(&qv);
    }
  }

  // ---- Phase B2: g -> gpk[4][2][2] packed regs (O lane layout) ----
  unsigned gpk[4][2][2];
  {
    bf16x8 bfg[2][4];
    float gb[2];
    #pragma unroll
    for (int jt = 0; jt < 2; ++jt) {
      #pragma unroll
      for (int kt = 0; kt < 4; ++kt)
        bfg[jt][kt] = *reinterpret_cast<const bf16x8*>(
            &wgT[(size_t)(h * 32 + jt * 16 + lr) * 128 + kt * 32 + lg * 8]);
      gb[jt] = bg[h * 32 + jt * 16 + lr];
    }
    #pragma unroll
    for (int it = 0; it < 4; ++it) {
      bf16x8 af[4];
      #pragma unroll
      for (int kt = 0; kt < 4; ++kt) {
        const int i = iq * 64 + it * 16 + lr;
        int byte = i * 256 + (kt * 64 + lg * 16);
        byte ^= ((i & 15) << 4);
        af[kt] = *reinterpret_cast<const bf16x8*>(zkb + byte);
      }
      f32x4 ga[2];
      ga[0] = (f32x4){0.f, 0.f, 0.f, 0.f};
      ga[1] = (f32x4){0.f, 0.f, 0.f, 0.f};
      #pragma unroll
      for (int kt = 0; kt < 4; ++kt)
        #pragma unroll
        for (int jt = 0; jt < 2; ++jt)
          ga[jt] = __builtin_amdgcn_mfma_f32_16x16x32_bf16(af[kt], bfg[jt][kt], ga[jt], 0, 0, 0);
      #pragma unroll
      for (int jt = 0; jt < 2; ++jt) {
        gpk[it][jt][0] = cvtpk(sigmoidf_(ga[jt][0] + gb[jt]), sigmoidf_(ga[jt][1] + gb[jt]));
        gpk[it][jt][1] = cvtpk(sigmoidf_(ga[jt][2] + gb[jt]), sigmoidf_(ga[jt][3] + gb[jt]));
      }
    }
  }

  // ---- Phase B3: V -> R2 LDS [ch][ii] (wave = (chq, vq)) ----
  {
    const int chq = w16 & 3, vq = w16 >> 2;
    bf16x8 bfv[2][4];
    float vb[2];
    #pragma unroll
    for (int jt = 0; jt < 2; ++jt) {
      #pragma unroll
      for (int kt = 0; kt < 4; ++kt)
        bfv[jt][kt] = *reinterpret_cast<const bf16x8*>(
            &wvT[(size_t)(chq * 32 + jt * 16 + lr) * 128 + kt * 32 + lg * 8]);
      vb[jt] = bv[chq * 32 + jt * 16 + lr];
    }
    #pragma unroll
    for (int it = 0; it < 4; ++it) {
      bf16x8 af[4];
      #pragma unroll
      for (int kt = 0; kt < 4; ++kt) {
        const int i = vq * 64 + it * 16 + lr;
        int byte = i * 256 + (kt * 64 + lg * 16);
        byte ^= ((i & 15) << 4);
        af[kt] = *reinterpret_cast<const bf16x8*>(zkb + byte);
      }
      f32x4 va[2];
      va[0] = (f32x4){0.f, 0.f, 0.f, 0.f};
      va[1] = (f32x4){0.f, 0.f, 0.f, 0.f};
      #pragma unroll
      for (int kt = 0; kt < 4; ++kt)
        #pragma unroll
        for (int jt = 0; jt < 2; ++jt)
          va[jt] = __builtin_amdgcn_mfma_f32_16x16x32_bf16(af[kt], bfv[jt][kt], va[jt], 0, 0, 0);
      const int ii0 = vq * 64 + it * 16 + lg * 4;
      #pragma unroll
      for (int jt = 0; jt < 2; ++jt) {
        const int ch = chq * 32 + jt * 16 + lr;
        uint2 pv;
        pv.x = cvtpk(va[jt][0] + vb[jt], va[jt][1] + vb[jt]);
        pv.y = cvtpk(va[jt][2] + vb[jt], va[jt][3] + vb[jt]);
        int byte = ch * 512 + ii0 * 2;
        byte ^= ((ch & 7) << 4);
        *reinterpret_cast<uint2*>(vtb + byte) = pv;
      }
    }
  }

  // ---- Phase C: K over R1 in place, wave = (cho, rh); 2 chunks of 64 rows ----
  {
    const int cho = w16 & 7, rh = w16 >> 3;
    bf16x8 bfk[4];
    #pragma unroll
    for (int kt = 0; kt < 4; ++kt)
      bfk[kt] = *reinterpret_cast<const bf16x8*>(
          &wkT[(size_t)(cho * 16 + lr) * 128 + kt * 32 + lg * 8]);
    const float4 kb4 = *reinterpret_cast<const float4*>(&bk[cho * 16 + lg * 4]);
    const float kb[4] = {kb4.x, kb4.y, kb4.z, kb4.w};

    #pragma unroll 1
    for (int c = 0; c < 2; ++c) {
      bf16x8 afr[4][4];
      #pragma unroll
      for (int itc = 0; itc < 4; ++itc)
        #pragma unroll
        for (int kt = 0; kt < 4; ++kt) {
          const int i = rh * 128 + c * 64 + itc * 16 + lr;
          int byte = i * 256 + (kt * 64 + lg * 16);
          byte ^= ((i & 15) << 4);
          afr[itc][kt] = *reinterpret_cast<const bf16x8*>(zkb + byte);
        }
      __syncthreads();   // all reads of these rows done (all waves)
      #pragma unroll
      for (int itc = 0; itc < 4; ++itc) {
        f32x4 ka = (f32x4){0.f, 0.f, 0.f, 0.f};
        #pragma unroll
        for (int kt = 0; kt < 4; ++kt)
          ka = __builtin_amdgcn_mfma_f32_16x16x32_bf16(bfk[kt], afr[itc][kt], ka, 0, 0, 0);
        const int j = rh * 128 + c * 64 + itc * 16 + lr;
        uint2 pkk;
        pkk.x = cvtpk(ka[0] + kb[0], ka[1] + kb[1]);
        pkk.y = cvtpk(ka[2] + kb[2], ka[3] + kb[3]);
        int byte = j * 256 + (cho * 16 + lg * 4) * 2;
        byte ^= ((j & 15) << 4);
        *reinterpret_cast<uint2*>(zkb + byte) = pkk;
      }
      __syncthreads();   // K rows visible before next chunk / attention
    }
  }

  // ---- Phase D: attention per (h, iq); 4 i-tiles; quarter-fused, FULL unroll ----
  #pragma unroll
  for (int it = 0; it < 4; ++it) {
    float psum = 0.f;
    f32x4 oacc[2];
    oacc[0] = (f32x4){0.f, 0.f, 0.f, 0.f};
    oacc[1] = (f32x4){0.f, 0.f, 0.f, 0.f};

    #pragma unroll
    for (int qr = 0; qr < 4; ++qr) {
      // QK^T for this quarter (4 j-tiles)
      f32x4 sacc[4];
      #pragma unroll
      for (int jj = 0; jj < 4; ++jj) sacc[jj] = (f32x4){0.f, 0.f, 0.f, 0.f};
      #pragma unroll
      for (int jj = 0; jj < 4; ++jj) {
        const int j = (qr * 4 + jj) * 16 + lr;
        int byte = j * 256 + h * 64 + lg * 16;
        byte ^= ((j & 15) << 4);
        bf16x8 kf = *reinterpret_cast<const bf16x8*>(zkb + byte);
        sacc[jj] = __builtin_amdgcn_mfma_f32_16x16x32_bf16(kf, qfrag[it], sacc[jj], 0, 0, 0);
      }
      // exp + psum (normalization deferred)
      #pragma unroll
      for (int jj = 0; jj < 4; ++jj)
        #pragma unroll
        for (int r = 0; r < 4; ++r) {
          const float e = __expf(sacc[jj][r]);
          sacc[jj][r] = e;
          psum += e;
        }
      // pack unnormalized P quarter
      #pragma unroll
      for (int jj = 0; jj < 4; ++jj) {
        uint2 pk;
        pk.x = cvtpk(sacc[jj][0], sacc[jj][1]);
        pk.y = cvtpk(sacc[jj][2], sacc[jj][3]);
        int byte = lr * 128 + (jj * 16 + lg * 4) * 2;
        byte ^= ((lr & 7) << 4);
        *reinterpret_cast<uint2*>(plb + byte) = pk;
      }
      asm volatile("s_waitcnt lgkmcnt(0)" ::: "memory");
      __builtin_amdgcn_sched_barrier(0);
      // PV for this quarter
      #pragma unroll
      for (int kq = 0; kq < 2; ++kq) {
        int pbyte = lr * 128 + (kq * 64 + lg * 16);
        pbyte ^= ((lr & 7) << 4);
        bf16x8 pf = *reinterpret_cast<const bf16x8*>(plb + pbyte);
        #pragma unroll
        for (int cht = 0; cht < 2; ++cht) {
          const int ch = h * 32 + cht * 16 + lr;
          int vbyte = ch * 512 + (qr * 128 + kq * 64 + lg * 16);
          vbyte ^= ((ch & 7) << 4);
          bf16x8 vf = *reinterpret_cast<const bf16x8*>(vtb + vbyte);
          oacc[cht] = __builtin_amdgcn_mfma_f32_16x16x32_bf16(pf, vf, oacc[cht], 0, 0, 0);
        }
      }
    }

    // row-sum across the 4 lane-groups sharing a row
    psum += __shfl_xor(psum, 16);
    psum += __shfl_xor(psum, 32);
    const float rl = 1.0f / psum;

    // ---- gate (from regs) + deferred normalize + store og [pos][128] ----
    #pragma unroll
    for (int cht = 0; cht < 2; ++cht)
      #pragma unroll
      for (int r = 0; r < 4; ++r) {
        const int i = iq * 64 + it * 16 + lg * 4 + r;
        const float gv = bf2f((unsigned short)((gpk[it][cht][r >> 1] >> ((r & 1) * 16)) & 0xffff));
        const size_t off = ((size_t)(n * Lc + i)) * 128 + h * 32 + cht * 16 + lr;
        og_ws[off] = f2bf(oacc[cht][r] * rl * gv);
      }
  }
}

// ---------------------------------------------------------------------------
// K3: out^T = w2^T · (o·g)^T  -> out[c][pos] fp32, coalesced along pos.
// ---------------------------------------------------------------------------
__global__ __launch_bounds__(256) void outproj_mfma(
    const unsigned short* __restrict__ og_ws,
    const unsigned short* __restrict__ w2T, const float* __restrict__ b2,
    float* __restrict__ out)
{
  const int t = threadIdx.x;
  const int w = t >> 6, l = t & 63, lr = l & 15, lg = l >> 4;
  const int pos = blockIdx.x * 64 + w * 16 + lr;

  bf16x8 zb[4];
  #pragma unroll
  for (int kt = 0; kt < 4; ++kt)
    zb[kt] = *reinterpret_cast<const bf16x8*>(
        &og_ws[(size_t)pos * 128 + kt * 32 + lg * 8]);

  #pragma unroll
  for (int ct = 0; ct < 8; ++ct) {
    f32x4 acc = (f32x4){0.f, 0.f, 0.f, 0.f};
    #pragma unroll
    for (int kt = 0; kt < 4; ++kt) {
      bf16x8 af = *reinterpret_cast<const bf16x8*>(
          &w2T[(size_t)(ct * 16 + lr) * 128 + kt * 32 + lg * 8]);
      acc = __builtin_amdgcn_mfma_f32_16x16x32_bf16(af, zb[kt], acc, 0, 0, 0);
    }
    #pragma unroll
    for (int r = 0; r < 4; ++r) {
      const int c = ct * 16 + lg * 4 + r;
      out[(size_t)c * NPOSc + pos] = acc[r] + b2[c];
    }
  }
}

// ---------------------------------------------------------------------------
extern "C" void kernel_launch(void* const* d_in, const int* in_sizes, int n_in,
                              void* d_out, int out_size, void* d_ws, size_t ws_size,
                              hipStream_t stream) {
  const float* z   = (const float*)d_in[0];
  const float* lnw = (const float*)d_in[1];
  const float* lnb = (const float*)d_in[2];
  const float* wq  = (const float*)d_in[3];
  const float* bq  = (const float*)d_in[4];
  const float* wk  = (const float*)d_in[5];
  const float* bk  = (const float*)d_in[6];
  const float* wv  = (const float*)d_in[7];
  const float* bv  = (const float*)d_in[8];
  const float* wg  = (const float*)d_in[9];
  const float* bg  = (const float*)d_in[10];
  const float* w2  = (const float*)d_in[11];
  const float* b2  = (const float*)d_in[12];
  float* out = (float*)d_out;

  const size_t S = (size_t)NPOSc * DHCc;        // 8388608 elements
  unsigned short* ws = (unsigned short*)d_ws;
  unsigned short* og_ws = ws;                   // [pos][128] gated attn output
  unsigned short* wT    = ws + S;               // 5 x 16384 bf16 weights

  prep_weights<<<5, 256, 0, stream>>>(wq, wk, wv, wg, w2, wT);
  fused_ln_proj_attn<<<Lc, 1024, 0, stream>>>(
      z, lnw, lnb, wT, bq, bk, bv, bg, og_ws);
  outproj_mfma<<<NPOSc / 64, 256, 0, stream>>>(
      og_ws, wT + 4 * (DZc * DHCc), b2, out);
}

// Round 17
// 87.062 us; speedup vs baseline: 1.0739x; 1.0739x over previous
//
#include <hip/hip_runtime.h>
#include <cstdint>
#include <cstddef>

#define DZc   128
#define Lc    256
#define Hc    4
#define DCc   32
#define DHCc  128
#define NPOSc (Lc * Lc)

typedef __attribute__((ext_vector_type(8))) short bf16x8;
typedef __attribute__((ext_vector_type(4))) short bf16x4;
typedef __attribute__((ext_vector_type(4))) float f32x4;

static __device__ __forceinline__ unsigned short f2bf(float f) {
  unsigned u = __float_as_uint(f);
  u += 0x7FFFu + ((u >> 16) & 1u);     // round-to-nearest-even
  return (unsigned short)(u >> 16);
}
static __device__ __forceinline__ float bf2f(unsigned short h) {
  return __uint_as_float(((unsigned)h) << 16);
}
static __device__ __forceinline__ float sigmoidf_(float x) {
  return 1.0f / (1.0f + __expf(-x));
}
// HW packed f32->bf16 (RNE, bit-identical to f2bf): 1 instr instead of ~8.
static __device__ __forceinline__ unsigned cvtpk(float lo, float hi) {
  unsigned r;
  asm("v_cvt_pk_bf16_f32 %0, %1, %2" : "=v"(r) : "v"(lo), "v"(hi));
  return r;
}

// ---------------------------------------------------------------------------
// prep: weights fp32 [k][j] -> bf16 transposed [j][k]; q-scale folded into wq.
// slot 0..3 = wq,wk,wv,wg ; slot 4 = w2 (-> w2T[c][k]).
// ---------------------------------------------------------------------------
__global__ __launch_bounds__(256) void prep_weights(
    const float* __restrict__ wq, const float* __restrict__ wk,
    const float* __restrict__ wv, const float* __restrict__ wg,
    const float* __restrict__ w2, unsigned short* __restrict__ wT)
{
  const int b = blockIdx.x;  // 0..4
  const int t = threadIdx.x;
  const float* src = (b == 0) ? wq : (b == 1) ? wk : (b == 2) ? wv : (b == 3) ? wg : w2;
  unsigned short* dst = wT + (size_t)b * (DZc * DHCc);
  const float scale = (b == 0) ? 0.17677669529663687f : 1.0f;  // sqrt(1/32)
  for (int p = 0; p < 64; ++p) {
    const int idx = p * 256 + t;             // 16384 elements
    const int kk = idx >> 7, j = idx & 127;  // src[kk][j]
    dst[j * 128 + kk] = f2bf(src[idx] * scale);
  }
}

// ---------------------------------------------------------------------------
// FUSED kernel, R17: block = (n, head-pair). 512 blocks x 512 thr (8 waves).
//   LDS = 80 KB exactly (zn 64KB reused as K[256][64]+V^T[64][256], pll 16KB)
//   -> 2 blocks/CU -> 16 waves/CU, WITH the proven (512,2)/VGPR-128 shape
//   (R13-R16 lesson: 1024-thr blocks always got VGPR=64 + spills).
//   K and V are computed into REGISTERS while zn is live, then written over
//   zn after a barrier. z is read twice per n (L2 absorbs; blocks paired).
// ---------------------------------------------------------------------------
__global__ __launch_bounds__(512, 2) void fused_ln_proj_attn(
    const float* __restrict__ z, const float* __restrict__ lnw, const float* __restrict__ lnb,
    const unsigned short* __restrict__ wT,
    const float* __restrict__ bq, const float* __restrict__ bk,
    const float* __restrict__ bv, const float* __restrict__ bg,
    unsigned short* __restrict__ og_ws)
{
  __shared__ unsigned short zkv[Lc * DZc];     // 64 KB: zn; later K(32K)+V^T(32K)
  __shared__ unsigned short pll[8][16 * 64];   // 16 KB: per-wave P quarter

  const int t   = threadIdx.x;
  const int bid = blockIdx.x;
  const int n   = bid >> 1;
  const int hp  = bid & 1;        // head pair (heads 2hp, 2hp+1)
  const int w8  = t >> 6;
  const int l   = t & 63;
  const int lr  = l & 15;
  const int lg  = l >> 4;
  const int hh  = w8 & 1;         // head within pair (q/g/V/D waves)
  const int iqq = w8 >> 1;        // row quarter (q/g/V/D waves)
  const int h   = hp * 2 + hh;    // global head

  char* zkb = reinterpret_cast<char*>(zkv);
  char* plb = reinterpret_cast<char*>(&pll[w8][0]);

  // ---- Phase A: LN (in-register stats, 16-lane shfl tree), 2 passes ----
  #pragma unroll
  for (int p = 0; p < 2; ++p) {
    const int pq = t >> 4;          // 0..31 pos-quad
    const int cg = t & 15;          // 0..15 channel group (8 ch)
    const int gp = n * 256 + p * 128 + pq * 4;
    const int cbase = cg * 8;

    float4 zr[8];
    #pragma unroll
    for (int cc = 0; cc < 8; ++cc)
      zr[cc] = *reinterpret_cast<const float4*>(&z[(size_t)(cbase + cc) * NPOSc + gp]);

    float s[4] = {0.f, 0.f, 0.f, 0.f}, s2[4] = {0.f, 0.f, 0.f, 0.f};
    #pragma unroll
    for (int cc = 0; cc < 8; ++cc) {
      s[0] += zr[cc].x; s2[0] += zr[cc].x * zr[cc].x;
      s[1] += zr[cc].y; s2[1] += zr[cc].y * zr[cc].y;
      s[2] += zr[cc].z; s2[2] += zr[cc].z * zr[cc].z;
      s[3] += zr[cc].w; s2[3] += zr[cc].w * zr[cc].w;
    }
    #pragma unroll
    for (int m = 1; m <= 8; m <<= 1) {
      #pragma unroll
      for (int e = 0; e < 4; ++e) {
        s[e]  += __shfl_xor(s[e],  m);
        s2[e] += __shfl_xor(s2[e], m);
      }
    }
    float mu[4], rs[4];
    #pragma unroll
    for (int e = 0; e < 4; ++e) {
      mu[e] = s[e] * (1.0f / DZc);
      const float var = s2[e] * (1.0f / DZc) - mu[e] * mu[e];
      rs[e] = rsqrtf(var + 1e-5f);
    }
    float lw[8], lb[8];
    #pragma unroll
    for (int q4 = 0; q4 < 2; ++q4) {
      const float4 a = *reinterpret_cast<const float4*>(&lnw[cbase + q4 * 4]);
      const float4 b = *reinterpret_cast<const float4*>(&lnb[cbase + q4 * 4]);
      lw[q4 * 4 + 0] = a.x; lw[q4 * 4 + 1] = a.y; lw[q4 * 4 + 2] = a.z; lw[q4 * 4 + 3] = a.w;
      lb[q4 * 4 + 0] = b.x; lb[q4 * 4 + 1] = b.y; lb[q4 * 4 + 2] = b.z; lb[q4 * 4 + 3] = b.w;
    }
    #pragma unroll
    for (int e = 0; e < 4; ++e) {
      const int i = p * 128 + pq * 4 + e;
      float zn[8];
      #pragma unroll
      for (int cc = 0; cc < 8; ++cc) {
        const float zc = (e == 0) ? zr[cc].x : (e == 1) ? zr[cc].y
                       : (e == 2) ? zr[cc].z : zr[cc].w;
        zn[cc] = (zc - mu[e]) * rs[e] * lw[cc] + lb[cc];
      }
      uint4 pw;
      pw.x = cvtpk(zn[0], zn[1]); pw.y = cvtpk(zn[2], zn[3]);
      pw.z = cvtpk(zn[4], zn[5]); pw.w = cvtpk(zn[6], zn[7]);
      int byte = i * 256 + cbase * 2;
      byte ^= ((i & 15) << 4);
      *reinterpret_cast<uint4*>(zkb + byte) = pw;
    }
  }
  __syncthreads();

  const unsigned short* wqT = wT;
  const unsigned short* wkT = wT + 1 * (DZc * DHCc);
  const unsigned short* wvT = wT + 2 * (DZc * DHCc);
  const unsigned short* wgT = wT + 3 * (DZc * DHCc);

  // ---- Phase B1: q -> qfrag[4] regs (attn B-frag layout), head h ----
  bf16x8 qfrag[4];
  {
    bf16x8 bfq[2][4];
    float4 qb4[2];
    #pragma unroll
    for (int jt = 0; jt < 2; ++jt) {
      #pragma unroll
      for (int kt = 0; kt < 4; ++kt)
        bfq[jt][kt] = *reinterpret_cast<const bf16x8*>(
            &wqT[(size_t)(h * 32 + jt * 16 + lr) * 128 + kt * 32 + lg * 8]);
      qb4[jt] = *reinterpret_cast<const float4*>(&bq[h * 32 + jt * 16 + lg * 4]);
      qb4[jt].x *= 0.17677669529663687f; qb4[jt].y *= 0.17677669529663687f;
      qb4[jt].z *= 0.17677669529663687f; qb4[jt].w *= 0.17677669529663687f;
    }
    #pragma unroll
    for (int it = 0; it < 4; ++it) {
      bf16x8 af[4];
      #pragma unroll
      for (int kt = 0; kt < 4; ++kt) {
        const int i = iqq * 64 + it * 16 + lr;
        int byte = i * 256 + (kt * 64 + lg * 16);
        byte ^= ((i & 15) << 4);
        af[kt] = *reinterpret_cast<const bf16x8*>(zkb + byte);
      }
      f32x4 qa[2];
      qa[0] = (f32x4){0.f, 0.f, 0.f, 0.f};
      qa[1] = (f32x4){0.f, 0.f, 0.f, 0.f};
      #pragma unroll
      for (int kt = 0; kt < 4; ++kt)
        #pragma unroll
        for (int jt = 0; jt < 2; ++jt)
          qa[jt] = __builtin_amdgcn_mfma_f32_16x16x32_bf16(bfq[jt][kt], af[kt], qa[jt], 0, 0, 0);
      unsigned srcw0[2], srcw1[2];
      srcw0[0] = cvtpk(qa[0][0] + qb4[0].x, qa[0][1] + qb4[0].y);
      srcw0[1] = cvtpk(qa[0][2] + qb4[0].z, qa[0][3] + qb4[0].w);
      srcw1[0] = cvtpk(qa[1][0] + qb4[1].x, qa[1][1] + qb4[1].y);
      srcw1[1] = cvtpk(qa[1][2] + qb4[1].z, qa[1][3] + qb4[1].w);
      // shuffle to qfrag: lane wants row lr, ch octet lg*8 (quad 2lg, 2lg+1)
      unsigned qw[4];
      #pragma unroll
      for (int i4 = 0; i4 < 4; ++i4) {
        const int quad = lg * 2 + (i4 >> 1);
        const int srcl = (quad & 3) * 16 + lr;
        const unsigned a = (unsigned)__shfl((int)srcw0[i4 & 1], srcl);
        const unsigned b = (unsigned)__shfl((int)srcw1[i4 & 1], srcl);
        qw[i4] = (lg >= 2) ? b : a;   // jt_src = quad>>2 == (lg>=2)
      }
      uint4 qv; qv.x = qw[0]; qv.y = qw[1]; qv.z = qw[2]; qv.w = qw[3];
      qfrag[it] = *reinterpret_cast<const bf16x8*>(&qv);
    }
  }

  // ---- Phase B2: g -> gpk[4][2][2] packed regs (O lane layout), head h ----
  unsigned gpk[4][2][2];
  {
    bf16x8 bfg[2][4];
    float gb[2];
    #pragma unroll
    for (int jt = 0; jt < 2; ++jt) {
      #pragma unroll
      for (int kt = 0; kt < 4; ++kt)
        bfg[jt][kt] = *reinterpret_cast<const bf16x8*>(
            &wgT[(size_t)(h * 32 + jt * 16 + lr) * 128 + kt * 32 + lg * 8]);
      gb[jt] = bg[h * 32 + jt * 16 + lr];
    }
    #pragma unroll
    for (int it = 0; it < 4; ++it) {
      bf16x8 af[4];
      #pragma unroll
      for (int kt = 0; kt < 4; ++kt) {
        const int i = iqq * 64 + it * 16 + lr;
        int byte = i * 256 + (kt * 64 + lg * 16);
        byte ^= ((i & 15) << 4);
        af[kt] = *reinterpret_cast<const bf16x8*>(zkb + byte);
      }
      f32x4 ga[2];
      ga[0] = (f32x4){0.f, 0.f, 0.f, 0.f};
      ga[1] = (f32x4){0.f, 0.f, 0.f, 0.f};
      #pragma unroll
      for (int kt = 0; kt < 4; ++kt)
        #pragma unroll
        for (int jt = 0; jt < 2; ++jt)
          ga[jt] = __builtin_amdgcn_mfma_f32_16x16x32_bf16(af[kt], bfg[jt][kt], ga[jt], 0, 0, 0);
      #pragma unroll
      for (int jt = 0; jt < 2; ++jt) {
        gpk[it][jt][0] = cvtpk(sigmoidf_(ga[jt][0] + gb[jt]), sigmoidf_(ga[jt][1] + gb[jt]));
        gpk[it][jt][1] = cvtpk(sigmoidf_(ga[jt][2] + gb[jt]), sigmoidf_(ga[jt][3] + gb[jt]));
      }
    }
  }

  // ---- Phase B3: V -> REGS (head hh of pair, rows iqq*64..) ----
  uint2 vreg[4][2];
  {
    bf16x8 bfv[2][4];
    float vb[2];
    #pragma unroll
    for (int jt = 0; jt < 2; ++jt) {
      #pragma unroll
      for (int kt = 0; kt < 4; ++kt)
        bfv[jt][kt] = *reinterpret_cast<const bf16x8*>(
            &wvT[(size_t)(h * 32 + jt * 16 + lr) * 128 + kt * 32 + lg * 8]);
      vb[jt] = bv[h * 32 + jt * 16 + lr];
    }
    #pragma unroll
    for (int it = 0; it < 4; ++it) {
      bf16x8 af[4];
      #pragma unroll
      for (int kt = 0; kt < 4; ++kt) {
        const int i = iqq * 64 + it * 16 + lr;
        int byte = i * 256 + (kt * 64 + lg * 16);
        byte ^= ((i & 15) << 4);
        af[kt] = *reinterpret_cast<const bf16x8*>(zkb + byte);
      }
      f32x4 va[2];
      va[0] = (f32x4){0.f, 0.f, 0.f, 0.f};
      va[1] = (f32x4){0.f, 0.f, 0.f, 0.f};
      #pragma unroll
      for (int kt = 0; kt < 4; ++kt)
        #pragma unroll
        for (int jt = 0; jt < 2; ++jt)
          va[jt] = __builtin_amdgcn_mfma_f32_16x16x32_bf16(af[kt], bfv[jt][kt], va[jt], 0, 0, 0);
      #pragma unroll
      for (int jt = 0; jt < 2; ++jt) {
        vreg[it][jt].x = cvtpk(va[jt][0] + vb[jt], va[jt][1] + vb[jt]);
        vreg[it][jt].y = cvtpk(va[jt][2] + vb[jt], va[jt][3] + vb[jt]);
      }
    }
  }

  // ---- Phase B4: K -> REGS (wave = (cho 16-ch group of 64, rh row-half)) ----
  uint2 kreg[8];
  const int cho = w8 & 3, rh = w8 >> 2;
  {
    bf16x8 bfk[4];
    #pragma unroll
    for (int kt = 0; kt < 4; ++kt)
      bfk[kt] = *reinterpret_cast<const bf16x8*>(
          &wkT[(size_t)(hp * 64 + cho * 16 + lr) * 128 + kt * 32 + lg * 8]);
    const float4 kb4 = *reinterpret_cast<const float4*>(&bk[hp * 64 + cho * 16 + lg * 4]);
    #pragma unroll
    for (int itc = 0; itc < 8; ++itc) {
      bf16x8 af[4];
      #pragma unroll
      for (int kt = 0; kt < 4; ++kt) {
        const int i = rh * 128 + itc * 16 + lr;
        int byte = i * 256 + (kt * 64 + lg * 16);
        byte ^= ((i & 15) << 4);
        af[kt] = *reinterpret_cast<const bf16x8*>(zkb + byte);
      }
      f32x4 ka = (f32x4){0.f, 0.f, 0.f, 0.f};
      #pragma unroll
      for (int kt = 0; kt < 4; ++kt)
        ka = __builtin_amdgcn_mfma_f32_16x16x32_bf16(bfk[kt], af[kt], ka, 0, 0, 0);
      kreg[itc].x = cvtpk(ka[0] + kb4.x, ka[1] + kb4.y);
      kreg[itc].y = cvtpk(ka[2] + kb4.z, ka[3] + kb4.w);
    }
  }
  __syncthreads();   // all zn reads complete

  // ---- Phase C: write K [j][64ch] into bytes [0,32K), V^T [64ch][ii] at 32K ----
  #pragma unroll
  for (int itc = 0; itc < 8; ++itc) {
    const int j = rh * 128 + itc * 16 + lr;
    int byte = j * 128 + (cho * 16 + lg * 4) * 2;
    byte ^= ((j & 7) << 4);
    *reinterpret_cast<uint2*>(zkb + byte) = kreg[itc];
  }
  #pragma unroll
  for (int it = 0; it < 4; ++it)
    #pragma unroll
    for (int jt = 0; jt < 2; ++jt) {
      const int ch64 = hh * 32 + jt * 16 + lr;
      const int ii0 = iqq * 64 + it * 16 + lg * 4;
      int byte = 32768 + ch64 * 512 + ii0 * 2;
      byte ^= ((ch64 & 7) << 4);
      *reinterpret_cast<uint2*>(zkb + byte) = vreg[it][jt];
    }
  __syncthreads();   // K,V visible

  // ---- Phase D: attention per (hh, iqq); 4 i-tiles; quarter-fused ----
  #pragma unroll
  for (int it = 0; it < 4; ++it) {
    float psum = 0.f;
    f32x4 oacc[2];
    oacc[0] = (f32x4){0.f, 0.f, 0.f, 0.f};
    oacc[1] = (f32x4){0.f, 0.f, 0.f, 0.f};

    #pragma unroll
    for (int qr = 0; qr < 4; ++qr) {
      f32x4 sacc[4];
      #pragma unroll
      for (int jj = 0; jj < 4; ++jj) sacc[jj] = (f32x4){0.f, 0.f, 0.f, 0.f};
      #pragma unroll
      for (int jj = 0; jj < 4; ++jj) {
        const int j = (qr * 4 + jj) * 16 + lr;
        int byte = j * 128 + hh * 64 + lg * 16;
        byte ^= ((j & 7) << 4);
        bf16x8 kf = *reinterpret_cast<const bf16x8*>(zkb + byte);
        sacc[jj] = __builtin_amdgcn_mfma_f32_16x16x32_bf16(kf, qfrag[it], sacc[jj], 0, 0, 0);
      }
      #pragma unroll
      for (int jj = 0; jj < 4; ++jj)
        #pragma unroll
        for (int r = 0; r < 4; ++r) {
          const float e = __expf(sacc[jj][r]);
          sacc[jj][r] = e;
          psum += e;
        }
      #pragma unroll
      for (int jj = 0; jj < 4; ++jj) {
        uint2 pk;
        pk.x = cvtpk(sacc[jj][0], sacc[jj][1]);
        pk.y = cvtpk(sacc[jj][2], sacc[jj][3]);
        int byte = lr * 128 + (jj * 16 + lg * 4) * 2;
        byte ^= ((lr & 7) << 4);
        *reinterpret_cast<uint2*>(plb + byte) = pk;
      }
      asm volatile("s_waitcnt lgkmcnt(0)" ::: "memory");
      __builtin_amdgcn_sched_barrier(0);
      #pragma unroll
      for (int kq = 0; kq < 2; ++kq) {
        int pbyte = lr * 128 + (kq * 64 + lg * 16);
        pbyte ^= ((lr & 7) << 4);
        bf16x8 pf = *reinterpret_cast<const bf16x8*>(plb + pbyte);
        #pragma unroll
        for (int cht = 0; cht < 2; ++cht) {
          const int ch64 = hh * 32 + cht * 16 + lr;
          int vbyte = 32768 + ch64 * 512 + (qr * 128 + kq * 64 + lg * 16);
          vbyte ^= ((ch64 & 7) << 4);
          bf16x8 vf = *reinterpret_cast<const bf16x8*>(zkb + vbyte);
          oacc[cht] = __builtin_amdgcn_mfma_f32_16x16x32_bf16(pf, vf, oacc[cht], 0, 0, 0);
        }
      }
    }

    psum += __shfl_xor(psum, 16);
    psum += __shfl_xor(psum, 32);
    const float rl = 1.0f / psum;

    // ---- gate (from regs) + deferred normalize + store og [pos][128] ----
    #pragma unroll
    for (int cht = 0; cht < 2; ++cht)
      #pragma unroll
      for (int r = 0; r < 4; ++r) {
        const int i = iqq * 64 + it * 16 + lg * 4 + r;
        const float gv = bf2f((unsigned short)((gpk[it][cht][r >> 1] >> ((r & 1) * 16)) & 0xffff));
        const size_t off = ((size_t)(n * Lc + i)) * 128 + h * 32 + cht * 16 + lr;
        og_ws[off] = f2bf(oacc[cht][r] * rl * gv);
      }
  }
}

// ---------------------------------------------------------------------------
// K3: out^T = w2^T · (o·g)^T  -> out[c][pos] fp32, coalesced along pos.
// ---------------------------------------------------------------------------
__global__ __launch_bounds__(256) void outproj_mfma(
    const unsigned short* __restrict__ og_ws,
    const unsigned short* __restrict__ w2T, const float* __restrict__ b2,
    float* __restrict__ out)
{
  const int t = threadIdx.x;
  const int w = t >> 6, l = t & 63, lr = l & 15, lg = l >> 4;
  const int pos = blockIdx.x * 64 + w * 16 + lr;

  bf16x8 zb[4];
  #pragma unroll
  for (int kt = 0; kt < 4; ++kt)
    zb[kt] = *reinterpret_cast<const bf16x8*>(
        &og_ws[(size_t)pos * 128 + kt * 32 + lg * 8]);

  #pragma unroll
  for (int ct = 0; ct < 8; ++ct) {
    f32x4 acc = (f32x4){0.f, 0.f, 0.f, 0.f};
    #pragma unroll
    for (int kt = 0; kt < 4; ++kt) {
      bf16x8 af = *reinterpret_cast<const bf16x8*>(
          &w2T[(size_t)(ct * 16 + lr) * 128 + kt * 32 + lg * 8]);
      acc = __builtin_amdgcn_mfma_f32_16x16x32_bf16(af, zb[kt], acc, 0, 0, 0);
    }
    #pragma unroll
    for (int r = 0; r < 4; ++r) {
      const int c = ct * 16 + lg * 4 + r;
      out[(size_t)c * NPOSc + pos] = acc[r] + b2[c];
    }
  }
}

// ---------------------------------------------------------------------------
extern "C" void kernel_launch(void* const* d_in, const int* in_sizes, int n_in,
                              void* d_out, int out_size, void* d_ws, size_t ws_size,
                              hipStream_t stream) {
  const float* z   = (const float*)d_in[0];
  const float* lnw = (const float*)d_in[1];
  const float* lnb = (const float*)d_in[2];
  const float* wq  = (const float*)d_in[3];
  const float* bq  = (const float*)d_in[4];
  const float* wk  = (const float*)d_in[5];
  const float* bk  = (const float*)d_in[6];
  const float* wv  = (const float*)d_in[7];
  const float* bv  = (const float*)d_in[8];
  const float* wg  = (const float*)d_in[9];
  const float* bg  = (const float*)d_in[10];
  const float* w2  = (const float*)d_in[11];
  const float* b2  = (const float*)d_in[12];
  float* out = (float*)d_out;

  const size_t S = (size_t)NPOSc * DHCc;        // 8388608 elements
  unsigned short* ws = (unsigned short*)d_ws;
  unsigned short* og_ws = ws;                   // [pos][128] gated attn output
  unsigned short* wT    = ws + S;               // 5 x 16384 bf16 weights

  prep_weights<<<5, 256, 0, stream>>>(wq, wk, wv, wg, w2, wT);
  fused_ln_proj_attn<<<2 * Lc, 512, 0, stream>>>(
      z, lnw, lnb, wT, bq, bk, bv, bg, og_ws);
  outproj_mfma<<<NPOSc / 64, 256, 0, stream>>>(
      og_ws, wT + 4 * (DZc * DHCc), b2, out);
}

// Round 18
// 69.836 us; speedup vs baseline: 1.3388x; 1.2467x over previous
//
#include <hip/hip_runtime.h>
#include <cstdint>
#include <cstddef>

#define DZc   128
#define Lc    256
#define Hc    4
#define DCc   32
#define DHCc  128
#define NPOSc (Lc * Lc)

typedef __attribute__((ext_vector_type(8))) short bf16x8;
typedef __attribute__((ext_vector_type(4))) short bf16x4;
typedef __attribute__((ext_vector_type(4))) float f32x4;

static __device__ __forceinline__ unsigned short f2bf(float f) {
  unsigned u = __float_as_uint(f);
  u += 0x7FFFu + ((u >> 16) & 1u);     // round-to-nearest-even
  return (unsigned short)(u >> 16);
}
static __device__ __forceinline__ float bf2f(unsigned short h) {
  return __uint_as_float(((unsigned)h) << 16);
}
static __device__ __forceinline__ float sigmoidf_(float x) {
  return 1.0f / (1.0f + __expf(-x));
}
// HW packed f32->bf16 (RNE, bit-identical to f2bf): 1 instr instead of ~8.
static __device__ __forceinline__ unsigned cvtpk(float lo, float hi) {
  unsigned r;
  asm("v_cvt_pk_bf16_f32 %0, %1, %2" : "=v"(r) : "v"(lo), "v"(hi));
  return r;
}

// ---------------------------------------------------------------------------
// prep: weights fp32 [k][j] -> bf16 transposed [j][k]; q-scale folded into wq.
// slot 0..3 = wq,wk,wv,wg ; slot 4 = w2 (-> w2T[c][k]).
// ---------------------------------------------------------------------------
__global__ __launch_bounds__(256) void prep_weights(
    const float* __restrict__ wq, const float* __restrict__ wk,
    const float* __restrict__ wv, const float* __restrict__ wg,
    const float* __restrict__ w2, unsigned short* __restrict__ wT)
{
  const int b = blockIdx.x;  // 0..4
  const int t = threadIdx.x;
  const float* src = (b == 0) ? wq : (b == 1) ? wk : (b == 2) ? wv : (b == 3) ? wg : w2;
  unsigned short* dst = wT + (size_t)b * (DZc * DHCc);
  const float scale = (b == 0) ? 0.17677669529663687f : 1.0f;  // sqrt(1/32)
  for (int p = 0; p < 64; ++p) {
    const int idx = p * 256 + t;             // 16384 elements
    const int kk = idx >> 7, j = idx & 127;  // src[kk][j]
    dst[j * 128 + kk] = f2bf(src[idx] * scale);
  }
}

// ---------------------------------------------------------------------------
// FUSED kernel, R18 = R12 (best passing: 512 thr, 8 waves, VGPR 128, no
// spills) + Phase E: out-projection fused in. Block n's Phase D produces the
// COMPLETE og[256][128] tile, so after vmcnt+barrier each wave runs K3's
// exact GEMM for its 32 positions (og re-read is same-CU L1/L2-hot).
// R13-R17 lesson encoded: don't fight the allocator (1024-thr => VGPR 64 +
// spills) and don't duplicate LN (head-split => +16 MB FETCH).
// ---------------------------------------------------------------------------
__global__ __launch_bounds__(512, 2) void fused_ln_proj_attn(
    const float* __restrict__ z, const float* __restrict__ lnw, const float* __restrict__ lnb,
    const unsigned short* __restrict__ wT,
    const float* __restrict__ bq, const float* __restrict__ bk,
    const float* __restrict__ bv, const float* __restrict__ bg,
    const float* __restrict__ b2,
    unsigned short* __restrict__ og_ws, float* __restrict__ out)
{
  __shared__ unsigned short zkl[Lc * DZc];     // 64 KB: zn, later K [j][128ch]
  __shared__ unsigned short vtl[DHCc * Lc];    // 64 KB: V^T [ch][ii]
  __shared__ unsigned short pll[8][16 * 64];   // 16 KB: per-wave P quarter

  const int t  = threadIdx.x;
  const int n  = blockIdx.x;
  const int w8 = t >> 6;
  const int l  = t & 63;
  const int lr = l & 15;
  const int lg = l >> 4;
  const int h     = w8 & 3;      // head for q/g/attention
  const int ihalf = w8 >> 2;     // query-row half for q/g/attention

  char* zkb = reinterpret_cast<char*>(zkl);
  char* vtb = reinterpret_cast<char*>(vtl);
  char* plb = reinterpret_cast<char*>(&pll[w8][0]);

  // ---- Phase A: LN (in-register stats, 16-lane shfl tree), 2 passes ----
  #pragma unroll
  for (int p = 0; p < 2; ++p) {
    const int pq = t >> 4;          // 0..31 pos-quad
    const int cg = t & 15;          // 0..15 channel group (8 ch)
    const int gp = n * 256 + p * 128 + pq * 4;
    const int cbase = cg * 8;

    float4 zr[8];
    #pragma unroll
    for (int cc = 0; cc < 8; ++cc)
      zr[cc] = *reinterpret_cast<const float4*>(&z[(size_t)(cbase + cc) * NPOSc + gp]);

    float s[4] = {0.f, 0.f, 0.f, 0.f}, s2[4] = {0.f, 0.f, 0.f, 0.f};
    #pragma unroll
    for (int cc = 0; cc < 8; ++cc) {
      s[0] += zr[cc].x; s2[0] += zr[cc].x * zr[cc].x;
      s[1] += zr[cc].y; s2[1] += zr[cc].y * zr[cc].y;
      s[2] += zr[cc].z; s2[2] += zr[cc].z * zr[cc].z;
      s[3] += zr[cc].w; s2[3] += zr[cc].w * zr[cc].w;
    }
    #pragma unroll
    for (int m = 1; m <= 8; m <<= 1) {
      #pragma unroll
      for (int e = 0; e < 4; ++e) {
        s[e]  += __shfl_xor(s[e],  m);
        s2[e] += __shfl_xor(s2[e], m);
      }
    }
    float mu[4], rs[4];
    #pragma unroll
    for (int e = 0; e < 4; ++e) {
      mu[e] = s[e] * (1.0f / DZc);
      const float var = s2[e] * (1.0f / DZc) - mu[e] * mu[e];
      rs[e] = rsqrtf(var + 1e-5f);
    }
    float lw[8], lb[8];
    #pragma unroll
    for (int q4 = 0; q4 < 2; ++q4) {
      const float4 a = *reinterpret_cast<const float4*>(&lnw[cbase + q4 * 4]);
      const float4 b = *reinterpret_cast<const float4*>(&lnb[cbase + q4 * 4]);
      lw[q4 * 4 + 0] = a.x; lw[q4 * 4 + 1] = a.y; lw[q4 * 4 + 2] = a.z; lw[q4 * 4 + 3] = a.w;
      lb[q4 * 4 + 0] = b.x; lb[q4 * 4 + 1] = b.y; lb[q4 * 4 + 2] = b.z; lb[q4 * 4 + 3] = b.w;
    }
    #pragma unroll
    for (int e = 0; e < 4; ++e) {
      const int i = p * 128 + pq * 4 + e;
      float zn[8];
      #pragma unroll
      for (int cc = 0; cc < 8; ++cc) {
        const float zc = (e == 0) ? zr[cc].x : (e == 1) ? zr[cc].y
                       : (e == 2) ? zr[cc].z : zr[cc].w;
        zn[cc] = (zc - mu[e]) * rs[e] * lw[cc] + lb[cc];
      }
      uint4 pw;
      pw.x = cvtpk(zn[0], zn[1]); pw.y = cvtpk(zn[2], zn[3]);
      pw.z = cvtpk(zn[4], zn[5]); pw.w = cvtpk(zn[6], zn[7]);
      int byte = i * 256 + cbase * 2;
      byte ^= ((i & 15) << 4);
      *reinterpret_cast<uint4*>(zkb + byte) = pw;
    }
  }
  __syncthreads();

  const unsigned short* wqT = wT;
  const unsigned short* wkT = wT + 1 * (DZc * DHCc);
  const unsigned short* wvT = wT + 2 * (DZc * DHCc);
  const unsigned short* wgT = wT + 3 * (DZc * DHCc);

  // ---- Phase B1: q -> qfrag[8] regs (attn B-frag layout) ----
  bf16x8 qfrag[8];
  {
    bf16x8 bfq[2][4];
    float4 qb4[2];
    #pragma unroll
    for (int jt = 0; jt < 2; ++jt) {
      #pragma unroll
      for (int kt = 0; kt < 4; ++kt)
        bfq[jt][kt] = *reinterpret_cast<const bf16x8*>(
            &wqT[(size_t)(h * 32 + jt * 16 + lr) * 128 + kt * 32 + lg * 8]);
      qb4[jt] = *reinterpret_cast<const float4*>(&bq[h * 32 + jt * 16 + lg * 4]);
      qb4[jt].x *= 0.17677669529663687f; qb4[jt].y *= 0.17677669529663687f;
      qb4[jt].z *= 0.17677669529663687f; qb4[jt].w *= 0.17677669529663687f;
    }
    #pragma unroll
    for (int it = 0; it < 8; ++it) {
      bf16x8 af[4];
      #pragma unroll
      for (int kt = 0; kt < 4; ++kt) {
        const int i = ihalf * 128 + it * 16 + lr;
        int byte = i * 256 + (kt * 64 + lg * 16);
        byte ^= ((i & 15) << 4);
        af[kt] = *reinterpret_cast<const bf16x8*>(zkb + byte);
      }
      f32x4 qa[2];
      qa[0] = (f32x4){0.f, 0.f, 0.f, 0.f};
      qa[1] = (f32x4){0.f, 0.f, 0.f, 0.f};
      #pragma unroll
      for (int kt = 0; kt < 4; ++kt)
        #pragma unroll
        for (int jt = 0; jt < 2; ++jt)
          qa[jt] = __builtin_amdgcn_mfma_f32_16x16x32_bf16(bfq[jt][kt], af[kt], qa[jt], 0, 0, 0);
      // srcw[jt][w]: ch = h*32 + jt*16 + lg*4 + 2w+{0,1}, pos = lr
      unsigned srcw0[2], srcw1[2];
      srcw0[0] = cvtpk(qa[0][0] + qb4[0].x, qa[0][1] + qb4[0].y);
      srcw0[1] = cvtpk(qa[0][2] + qb4[0].z, qa[0][3] + qb4[0].w);
      srcw1[0] = cvtpk(qa[1][0] + qb4[1].x, qa[1][1] + qb4[1].y);
      srcw1[1] = cvtpk(qa[1][2] + qb4[1].z, qa[1][3] + qb4[1].w);
      // shuffle to qfrag: lane wants row lr, ch octet lg*8 (quad 2lg, 2lg+1)
      unsigned qw[4];
      #pragma unroll
      for (int i4 = 0; i4 < 4; ++i4) {
        const int quad = lg * 2 + (i4 >> 1);
        const int srcl = (quad & 3) * 16 + lr;
        const unsigned a = (unsigned)__shfl((int)srcw0[i4 & 1], srcl);
        const unsigned b = (unsigned)__shfl((int)srcw1[i4 & 1], srcl);
        qw[i4] = (lg >= 2) ? b : a;   // jt_src = quad>>2 == (lg>=2)
      }
      uint4 qv; qv.x = qw[0]; qv.y = qw[1]; qv.z = qw[2]; qv.w = qw[3];
      qfrag[it] = *reinterpret_cast<const bf16x8*>(&qv);
    }
  }

  // ---- Phase B2: g -> gpk[8][2][2] packed regs (O lane layout) ----
  unsigned gpk[8][2][2];
  {
    bf16x8 bfg[2][4];
    float gb[2];
    #pragma unroll
    for (int jt = 0; jt < 2; ++jt) {
      #pragma unroll
      for (int kt = 0; kt < 4; ++kt)
        bfg[jt][kt] = *reinterpret_cast<const bf16x8*>(
            &wgT[(size_t)(h * 32 + jt * 16 + lr) * 128 + kt * 32 + lg * 8]);
      gb[jt] = bg[h * 32 + jt * 16 + lr];
    }
    #pragma unroll
    for (int it = 0; it < 8; ++it) {
      bf16x8 af[4];
      #pragma unroll
      for (int kt = 0; kt < 4; ++kt) {
        const int i = ihalf * 128 + it * 16 + lr;
        int byte = i * 256 + (kt * 64 + lg * 16);
        byte ^= ((i & 15) << 4);
        af[kt] = *reinterpret_cast<const bf16x8*>(zkb + byte);
      }
      f32x4 ga[2];
      ga[0] = (f32x4){0.f, 0.f, 0.f, 0.f};
      ga[1] = (f32x4){0.f, 0.f, 0.f, 0.f};
      #pragma unroll
      for (int kt = 0; kt < 4; ++kt)
        #pragma unroll
        for (int jt = 0; jt < 2; ++jt)
          ga[jt] = __builtin_amdgcn_mfma_f32_16x16x32_bf16(af[kt], bfg[jt][kt], ga[jt], 0, 0, 0);
      #pragma unroll
      for (int jt = 0; jt < 2; ++jt) {
        gpk[it][jt][0] = cvtpk(sigmoidf_(ga[jt][0] + gb[jt]), sigmoidf_(ga[jt][1] + gb[jt]));
        gpk[it][jt][1] = cvtpk(sigmoidf_(ga[jt][2] + gb[jt]), sigmoidf_(ga[jt][3] + gb[jt]));
      }
    }
  }

  // ---- Phase B3: V -> R2 LDS [ch][ii] (wave = (chq, vih)) ----
  {
    const int chq = w8 & 3, vih = w8 >> 2;
    bf16x8 bfv[2][4];
    float vb[2];
    #pragma unroll
    for (int jt = 0; jt < 2; ++jt) {
      #pragma unroll
      for (int kt = 0; kt < 4; ++kt)
        bfv[jt][kt] = *reinterpret_cast<const bf16x8*>(
            &wvT[(size_t)(chq * 32 + jt * 16 + lr) * 128 + kt * 32 + lg * 8]);
      vb[jt] = bv[chq * 32 + jt * 16 + lr];
    }
    #pragma unroll 1
    for (int it = 0; it < 8; ++it) {
      bf16x8 af[4];
      #pragma unroll
      for (int kt = 0; kt < 4; ++kt) {
        const int i = vih * 128 + it * 16 + lr;
        int byte = i * 256 + (kt * 64 + lg * 16);
        byte ^= ((i & 15) << 4);
        af[kt] = *reinterpret_cast<const bf16x8*>(zkb + byte);
      }
      f32x4 va[2];
      va[0] = (f32x4){0.f, 0.f, 0.f, 0.f};
      va[1] = (f32x4){0.f, 0.f, 0.f, 0.f};
      #pragma unroll
      for (int kt = 0; kt < 4; ++kt)
        #pragma unroll
        for (int jt = 0; jt < 2; ++jt)
          va[jt] = __builtin_amdgcn_mfma_f32_16x16x32_bf16(af[kt], bfv[jt][kt], va[jt], 0, 0, 0);
      const int ii0 = vih * 128 + it * 16 + lg * 4;
      #pragma unroll
      for (int jt = 0; jt < 2; ++jt) {
        const int ch = chq * 32 + jt * 16 + lr;
        uint2 pv;
        pv.x = cvtpk(va[jt][0] + vb[jt], va[jt][1] + vb[jt]);
        pv.y = cvtpk(va[jt][2] + vb[jt], va[jt][3] + vb[jt]);
        int byte = ch * 512 + ii0 * 2;
        byte ^= ((ch & 7) << 4);
        *reinterpret_cast<uint2*>(vtb + byte) = pv;
      }
    }
  }

  // ---- Phase C: K over R1 in place, 4 chunks of 64 rows (wave = jt w8) ----
  {
    bf16x8 bfk[4];
    #pragma unroll
    for (int kt = 0; kt < 4; ++kt)
      bfk[kt] = *reinterpret_cast<const bf16x8*>(
          &wkT[(size_t)(w8 * 16 + lr) * 128 + kt * 32 + lg * 8]);
    const float4 kb4 = *reinterpret_cast<const float4*>(&bk[w8 * 16 + lg * 4]);
    const float kb[4] = {kb4.x, kb4.y, kb4.z, kb4.w};

    #pragma unroll 1
    for (int c = 0; c < 4; ++c) {
      bf16x8 afr[4][4];
      #pragma unroll
      for (int itc = 0; itc < 4; ++itc)
        #pragma unroll
        for (int kt = 0; kt < 4; ++kt) {
          const int i = c * 64 + itc * 16 + lr;
          int byte = i * 256 + (kt * 64 + lg * 16);
          byte ^= ((i & 15) << 4);
          afr[itc][kt] = *reinterpret_cast<const bf16x8*>(zkb + byte);
        }
      __syncthreads();   // all reads of these rows done (all waves)
      #pragma unroll
      for (int itc = 0; itc < 4; ++itc) {
        f32x4 ka = (f32x4){0.f, 0.f, 0.f, 0.f};
        #pragma unroll
        for (int kt = 0; kt < 4; ++kt)
          ka = __builtin_amdgcn_mfma_f32_16x16x32_bf16(bfk[kt], afr[itc][kt], ka, 0, 0, 0);
        const int j = c * 64 + itc * 16 + lr;
        uint2 pkk;
        pkk.x = cvtpk(ka[0] + kb[0], ka[1] + kb[1]);
        pkk.y = cvtpk(ka[2] + kb[2], ka[3] + kb[3]);
        int byte = j * 256 + (w8 * 16 + lg * 4) * 2;
        byte ^= ((j & 15) << 4);
        *reinterpret_cast<uint2*>(zkb + byte) = pkk;
      }
      __syncthreads();   // K rows visible before next chunk / attention
    }
  }

  // ---- Phase D: attention per (h, ihalf); 8 i-tiles of 16 query rows ----
  #pragma unroll
  for (int it = 0; it < 8; ++it) {
    // ---- S^T = K · Q^T over all 256 keys ----
    f32x4 sacc[16];
    #pragma unroll
    for (int jt = 0; jt < 16; ++jt) sacc[jt] = (f32x4){0.f, 0.f, 0.f, 0.f};
    #pragma unroll
    for (int jt = 0; jt < 16; ++jt) {
      const int j = jt * 16 + lr;
      int byte = j * 256 + h * 64 + lg * 16;
      byte ^= ((j & 15) << 4);
      bf16x8 kf = *reinterpret_cast<const bf16x8*>(zkb + byte);
      sacc[jt] = __builtin_amdgcn_mfma_f32_16x16x32_bf16(kf, qfrag[it], sacc[jt], 0, 0, 0);
    }

    // ---- max-free softmax: exp in place; NORMALIZATION DEFERRED past PV ----
    float psum = 0.f;
    #pragma unroll
    for (int jt = 0; jt < 16; ++jt)
      #pragma unroll
      for (int r = 0; r < 4; ++r) {
        const float e = __expf(sacc[jt][r]);
        sacc[jt][r] = e;
        psum += e;
      }
    psum += __shfl_xor(psum, 16);
    psum += __shfl_xor(psum, 32);
    const float rl = 1.0f / psum;

    // ---- PV in 4 quarter rounds (2KB/wave P buffer), unnormalized P ----
    f32x4 oacc[2];
    oacc[0] = (f32x4){0.f, 0.f, 0.f, 0.f};
    oacc[1] = (f32x4){0.f, 0.f, 0.f, 0.f};
    #pragma unroll
    for (int qr = 0; qr < 4; ++qr) {
      #pragma unroll
      for (int jj = 0; jj < 4; ++jj) {
        const int jt = qr * 4 + jj;
        uint2 pk;
        pk.x = cvtpk(sacc[jt][0], sacc[jt][1]);
        pk.y = cvtpk(sacc[jt][2], sacc[jt][3]);
        int byte = lr * 128 + (jj * 16 + lg * 4) * 2;
        byte ^= ((lr & 7) << 4);
        *reinterpret_cast<uint2*>(plb + byte) = pk;
      }
      asm volatile("s_waitcnt lgkmcnt(0)" ::: "memory");
      __builtin_amdgcn_sched_barrier(0);
      #pragma unroll
      for (int kq = 0; kq < 2; ++kq) {
        int pbyte = lr * 128 + (kq * 64 + lg * 16);
        pbyte ^= ((lr & 7) << 4);
        bf16x8 pf = *reinterpret_cast<const bf16x8*>(plb + pbyte);
        #pragma unroll
        for (int cht = 0; cht < 2; ++cht) {
          const int ch = h * 32 + cht * 16 + lr;
          int vbyte = ch * 512 + (qr * 128 + kq * 64 + lg * 16);
          vbyte ^= ((ch & 7) << 4);
          bf16x8 vf = *reinterpret_cast<const bf16x8*>(vtb + vbyte);
          oacc[cht] = __builtin_amdgcn_mfma_f32_16x16x32_bf16(pf, vf, oacc[cht], 0, 0, 0);
        }
      }
    }

    // ---- gate (from regs) + deferred normalize + store og [pos][128] ----
    #pragma unroll
    for (int cht = 0; cht < 2; ++cht)
      #pragma unroll
      for (int r = 0; r < 4; ++r) {
        const int i = ihalf * 128 + it * 16 + lg * 4 + r;
        const float gv = bf2f((unsigned short)((gpk[it][cht][r >> 1] >> ((r & 1) * 16)) & 0xffff));
        const size_t off = ((size_t)(n * Lc + i)) * 128 + h * 32 + cht * 16 + lr;
        og_ws[off] = f2bf(oacc[cht][r] * rl * gv);
      }
  }

  // ---- Phase E (fused K3): out^T = w2^T · og^T for this block's 256 pos ----
  asm volatile("s_waitcnt vmcnt(0)" ::: "memory");
  __syncthreads();     // all og writes of this block complete & visible
  {
    const unsigned short* w2T = wT + 4 * (DZc * DHCc);
    // load both pos-subtiles' og B-frags first (L1/L2-hot, just written here)
    bf16x8 zb[2][4];
    #pragma unroll
    for (int sub = 0; sub < 2; ++sub) {
      const size_t gpos = (size_t)n * 256 + w8 * 32 + sub * 16 + lr;
      #pragma unroll
      for (int kt = 0; kt < 4; ++kt)
        zb[sub][kt] = *reinterpret_cast<const bf16x8*>(
            &og_ws[gpos * 128 + kt * 32 + lg * 8]);
    }
    #pragma unroll
    for (int ct = 0; ct < 8; ++ct) {
      bf16x8 af[4];
      #pragma unroll
      for (int kt = 0; kt < 4; ++kt)
        af[kt] = *reinterpret_cast<const bf16x8*>(
            &w2T[(size_t)(ct * 16 + lr) * 128 + kt * 32 + lg * 8]);
      #pragma unroll
      for (int sub = 0; sub < 2; ++sub) {
        f32x4 acc = (f32x4){0.f, 0.f, 0.f, 0.f};
        #pragma unroll
        for (int kt = 0; kt < 4; ++kt)
          acc = __builtin_amdgcn_mfma_f32_16x16x32_bf16(af[kt], zb[sub][kt], acc, 0, 0, 0);
        const size_t gpos = (size_t)n * 256 + w8 * 32 + sub * 16 + lr;
        #pragma unroll
        for (int r = 0; r < 4; ++r) {
          const int c = ct * 16 + lg * 4 + r;
          out[(size_t)c * NPOSc + gpos] = acc[r] + b2[c];
        }
      }
    }
  }
}

// ---------------------------------------------------------------------------
extern "C" void kernel_launch(void* const* d_in, const int* in_sizes, int n_in,
                              void* d_out, int out_size, void* d_ws, size_t ws_size,
                              hipStream_t stream) {
  const float* z   = (const float*)d_in[0];
  const float* lnw = (const float*)d_in[1];
  const float* lnb = (const float*)d_in[2];
  const float* wq  = (const float*)d_in[3];
  const float* bq  = (const float*)d_in[4];
  const float* wk  = (const float*)d_in[5];
  const float* bk  = (const float*)d_in[6];
  const float* wv  = (const float*)d_in[7];
  const float* bv  = (const float*)d_in[8];
  const float* wg  = (const float*)d_in[9];
  const float* bg  = (const float*)d_in[10];
  const float* w2  = (const float*)d_in[11];
  const float* b2  = (const float*)d_in[12];
  float* out = (float*)d_out;

  const size_t S = (size_t)NPOSc * DHCc;        // 8388608 elements
  unsigned short* ws = (unsigned short*)d_ws;
  unsigned short* og_ws = ws;                   // [pos][128] gated attn output
  unsigned short* wT    = ws + S;               // 5 x 16384 bf16 weights

  prep_weights<<<5, 256, 0, stream>>>(wq, wk, wv, wg, w2, wT);
  fused_ln_proj_attn<<<Lc, 512, 0, stream>>>(
      z, lnw, lnb, wT, bq, bk, bv, bg, b2, og_ws, out);
}

// Round 19
// 69.717 us; speedup vs baseline: 1.3411x; 1.0017x over previous
//
#include <hip/hip_runtime.h>
#include <cstdint>
#include <cstddef>

#define DZc   128
#define Lc    256
#define Hc    4
#define DCc   32
#define DHCc  128
#define NPOSc (Lc * Lc)

typedef __attribute__((ext_vector_type(8))) short bf16x8;
typedef __attribute__((ext_vector_type(4))) short bf16x4;
typedef __attribute__((ext_vector_type(4))) float f32x4;

static __device__ __forceinline__ unsigned short f2bf(float f) {
  unsigned u = __float_as_uint(f);
  u += 0x7FFFu + ((u >> 16) & 1u);     // round-to-nearest-even
  return (unsigned short)(u >> 16);
}
static __device__ __forceinline__ float bf2f(unsigned short h) {
  return __uint_as_float(((unsigned)h) << 16);
}
static __device__ __forceinline__ float sigmoidf_(float x) {
  return 1.0f / (1.0f + __expf(-x));
}
// HW packed f32->bf16 (RNE, bit-identical to f2bf): 1 instr instead of ~8.
static __device__ __forceinline__ unsigned cvtpk(float lo, float hi) {
  unsigned r;
  asm("v_cvt_pk_bf16_f32 %0, %1, %2" : "=v"(r) : "v"(lo), "v"(hi));
  return r;
}

// ---------------------------------------------------------------------------
// prep: weights fp32 [k][j] -> bf16 transposed [j][k]; q-scale folded into wq.
// slot 0..3 = wq,wk,wv,wg ; slot 4 = w2 (-> w2T[c][k]).
// ---------------------------------------------------------------------------
__global__ __launch_bounds__(256) void prep_weights(
    const float* __restrict__ wq, const float* __restrict__ wk,
    const float* __restrict__ wv, const float* __restrict__ wg,
    const float* __restrict__ w2, unsigned short* __restrict__ wT)
{
  const int b = blockIdx.x;  // 0..4
  const int t = threadIdx.x;
  const float* src = (b == 0) ? wq : (b == 1) ? wk : (b == 2) ? wv : (b == 3) ? wg : w2;
  unsigned short* dst = wT + (size_t)b * (DZc * DHCc);
  const float scale = (b == 0) ? 0.17677669529663687f : 1.0f;  // sqrt(1/32)
  for (int p = 0; p < 64; ++p) {
    const int idx = p * 256 + t;             // 16384 elements
    const int kk = idx >> 7, j = idx & 127;  // src[kk][j]
    dst[j * 128 + kk] = f2bf(src[idx] * scale);
  }
}

// ---------------------------------------------------------------------------
// FUSED kernel, R19 = R18 with og kept ON-CHIP: Phase D packs gated output
// into 32 regs (ogpk), then og -> zkl LDS (K/V dead after D), Phase E reads
// B-frags from LDS. Deletes 16.7 MB og HBM writes + the vmcnt(0) global
// drain. launch_bounds(512,2) -> VGPR cap 256; LDS 144 KB already caps at
// 1 block/CU so the extra ~40 VGPRs are free.
// ---------------------------------------------------------------------------
__global__ __launch_bounds__(512, 2) void fused_ln_proj_attn(
    const float* __restrict__ z, const float* __restrict__ lnw, const float* __restrict__ lnb,
    const unsigned short* __restrict__ wT,
    const float* __restrict__ bq, const float* __restrict__ bk,
    const float* __restrict__ bv, const float* __restrict__ bg,
    const float* __restrict__ b2, float* __restrict__ out)
{
  __shared__ unsigned short zkl[Lc * DZc];     // 64 KB: zn -> K [j][128ch] -> og [pos][128ch]
  __shared__ unsigned short vtl[DHCc * Lc];    // 64 KB: V^T [ch][ii]
  __shared__ unsigned short pll[8][16 * 64];   // 16 KB: per-wave P quarter

  const int t  = threadIdx.x;
  const int n  = blockIdx.x;
  const int w8 = t >> 6;
  const int l  = t & 63;
  const int lr = l & 15;
  const int lg = l >> 4;
  const int h     = w8 & 3;      // head for q/g/attention
  const int ihalf = w8 >> 2;     // query-row half for q/g/attention

  char* zkb = reinterpret_cast<char*>(zkl);
  char* vtb = reinterpret_cast<char*>(vtl);
  char* plb = reinterpret_cast<char*>(&pll[w8][0]);

  // ---- Phase A: LN (in-register stats, 16-lane shfl tree), 2 passes ----
  #pragma unroll
  for (int p = 0; p < 2; ++p) {
    const int pq = t >> 4;          // 0..31 pos-quad
    const int cg = t & 15;          // 0..15 channel group (8 ch)
    const int gp = n * 256 + p * 128 + pq * 4;
    const int cbase = cg * 8;

    float4 zr[8];
    #pragma unroll
    for (int cc = 0; cc < 8; ++cc)
      zr[cc] = *reinterpret_cast<const float4*>(&z[(size_t)(cbase + cc) * NPOSc + gp]);

    float s[4] = {0.f, 0.f, 0.f, 0.f}, s2[4] = {0.f, 0.f, 0.f, 0.f};
    #pragma unroll
    for (int cc = 0; cc < 8; ++cc) {
      s[0] += zr[cc].x; s2[0] += zr[cc].x * zr[cc].x;
      s[1] += zr[cc].y; s2[1] += zr[cc].y * zr[cc].y;
      s[2] += zr[cc].z; s2[2] += zr[cc].z * zr[cc].z;
      s[3] += zr[cc].w; s2[3] += zr[cc].w * zr[cc].w;
    }
    #pragma unroll
    for (int m = 1; m <= 8; m <<= 1) {
      #pragma unroll
      for (int e = 0; e < 4; ++e) {
        s[e]  += __shfl_xor(s[e],  m);
        s2[e] += __shfl_xor(s2[e], m);
      }
    }
    float mu[4], rs[4];
    #pragma unroll
    for (int e = 0; e < 4; ++e) {
      mu[e] = s[e] * (1.0f / DZc);
      const float var = s2[e] * (1.0f / DZc) - mu[e] * mu[e];
      rs[e] = rsqrtf(var + 1e-5f);
    }
    float lw[8], lb[8];
    #pragma unroll
    for (int q4 = 0; q4 < 2; ++q4) {
      const float4 a = *reinterpret_cast<const float4*>(&lnw[cbase + q4 * 4]);
      const float4 b = *reinterpret_cast<const float4*>(&lnb[cbase + q4 * 4]);
      lw[q4 * 4 + 0] = a.x; lw[q4 * 4 + 1] = a.y; lw[q4 * 4 + 2] = a.z; lw[q4 * 4 + 3] = a.w;
      lb[q4 * 4 + 0] = b.x; lb[q4 * 4 + 1] = b.y; lb[q4 * 4 + 2] = b.z; lb[q4 * 4 + 3] = b.w;
    }
    #pragma unroll
    for (int e = 0; e < 4; ++e) {
      const int i = p * 128 + pq * 4 + e;
      float zn[8];
      #pragma unroll
      for (int cc = 0; cc < 8; ++cc) {
        const float zc = (e == 0) ? zr[cc].x : (e == 1) ? zr[cc].y
                       : (e == 2) ? zr[cc].z : zr[cc].w;
        zn[cc] = (zc - mu[e]) * rs[e] * lw[cc] + lb[cc];
      }
      uint4 pw;
      pw.x = cvtpk(zn[0], zn[1]); pw.y = cvtpk(zn[2], zn[3]);
      pw.z = cvtpk(zn[4], zn[5]); pw.w = cvtpk(zn[6], zn[7]);
      int byte = i * 256 + cbase * 2;
      byte ^= ((i & 15) << 4);
      *reinterpret_cast<uint4*>(zkb + byte) = pw;
    }
  }
  __syncthreads();

  const unsigned short* wqT = wT;
  const unsigned short* wkT = wT + 1 * (DZc * DHCc);
  const unsigned short* wvT = wT + 2 * (DZc * DHCc);
  const unsigned short* wgT = wT + 3 * (DZc * DHCc);

  // ---- Phase B1: q -> qfrag[8] regs (attn B-frag layout) ----
  bf16x8 qfrag[8];
  {
    bf16x8 bfq[2][4];
    float4 qb4[2];
    #pragma unroll
    for (int jt = 0; jt < 2; ++jt) {
      #pragma unroll
      for (int kt = 0; kt < 4; ++kt)
        bfq[jt][kt] = *reinterpret_cast<const bf16x8*>(
            &wqT[(size_t)(h * 32 + jt * 16 + lr) * 128 + kt * 32 + lg * 8]);
      qb4[jt] = *reinterpret_cast<const float4*>(&bq[h * 32 + jt * 16 + lg * 4]);
      qb4[jt].x *= 0.17677669529663687f; qb4[jt].y *= 0.17677669529663687f;
      qb4[jt].z *= 0.17677669529663687f; qb4[jt].w *= 0.17677669529663687f;
    }
    #pragma unroll
    for (int it = 0; it < 8; ++it) {
      bf16x8 af[4];
      #pragma unroll
      for (int kt = 0; kt < 4; ++kt) {
        const int i = ihalf * 128 + it * 16 + lr;
        int byte = i * 256 + (kt * 64 + lg * 16);
        byte ^= ((i & 15) << 4);
        af[kt] = *reinterpret_cast<const bf16x8*>(zkb + byte);
      }
      f32x4 qa[2];
      qa[0] = (f32x4){0.f, 0.f, 0.f, 0.f};
      qa[1] = (f32x4){0.f, 0.f, 0.f, 0.f};
      #pragma unroll
      for (int kt = 0; kt < 4; ++kt)
        #pragma unroll
        for (int jt = 0; jt < 2; ++jt)
          qa[jt] = __builtin_amdgcn_mfma_f32_16x16x32_bf16(bfq[jt][kt], af[kt], qa[jt], 0, 0, 0);
      // srcw[jt][w]: ch = h*32 + jt*16 + lg*4 + 2w+{0,1}, pos = lr
      unsigned srcw0[2], srcw1[2];
      srcw0[0] = cvtpk(qa[0][0] + qb4[0].x, qa[0][1] + qb4[0].y);
      srcw0[1] = cvtpk(qa[0][2] + qb4[0].z, qa[0][3] + qb4[0].w);
      srcw1[0] = cvtpk(qa[1][0] + qb4[1].x, qa[1][1] + qb4[1].y);
      srcw1[1] = cvtpk(qa[1][2] + qb4[1].z, qa[1][3] + qb4[1].w);
      // shuffle to qfrag: lane wants row lr, ch octet lg*8 (quad 2lg, 2lg+1)
      unsigned qw[4];
      #pragma unroll
      for (int i4 = 0; i4 < 4; ++i4) {
        const int quad = lg * 2 + (i4 >> 1);
        const int srcl = (quad & 3) * 16 + lr;
        const unsigned a = (unsigned)__shfl((int)srcw0[i4 & 1], srcl);
        const unsigned b = (unsigned)__shfl((int)srcw1[i4 & 1], srcl);
        qw[i4] = (lg >= 2) ? b : a;   // jt_src = quad>>2 == (lg>=2)
      }
      uint4 qv; qv.x = qw[0]; qv.y = qw[1]; qv.z = qw[2]; qv.w = qw[3];
      qfrag[it] = *reinterpret_cast<const bf16x8*>(&qv);
    }
  }

  // ---- Phase B2: g -> gpk[8][2][2] packed regs (O lane layout) ----
  unsigned gpk[8][2][2];
  {
    bf16x8 bfg[2][4];
    float gb[2];
    #pragma unroll
    for (int jt = 0; jt < 2; ++jt) {
      #pragma unroll
      for (int kt = 0; kt < 4; ++kt)
        bfg[jt][kt] = *reinterpret_cast<const bf16x8*>(
            &wgT[(size_t)(h * 32 + jt * 16 + lr) * 128 + kt * 32 + lg * 8]);
      gb[jt] = bg[h * 32 + jt * 16 + lr];
    }
    #pragma unroll
    for (int it = 0; it < 8; ++it) {
      bf16x8 af[4];
      #pragma unroll
      for (int kt = 0; kt < 4; ++kt) {
        const int i = ihalf * 128 + it * 16 + lr;
        int byte = i * 256 + (kt * 64 + lg * 16);
        byte ^= ((i & 15) << 4);
        af[kt] = *reinterpret_cast<const bf16x8*>(zkb + byte);
      }
      f32x4 ga[2];
      ga[0] = (f32x4){0.f, 0.f, 0.f, 0.f};
      ga[1] = (f32x4){0.f, 0.f, 0.f, 0.f};
      #pragma unroll
      for (int kt = 0; kt < 4; ++kt)
        #pragma unroll
        for (int jt = 0; jt < 2; ++jt)
          ga[jt] = __builtin_amdgcn_mfma_f32_16x16x32_bf16(af[kt], bfg[jt][kt], ga[jt], 0, 0, 0);
      #pragma unroll
      for (int jt = 0; jt < 2; ++jt) {
        gpk[it][jt][0] = cvtpk(sigmoidf_(ga[jt][0] + gb[jt]), sigmoidf_(ga[jt][1] + gb[jt]));
        gpk[it][jt][1] = cvtpk(sigmoidf_(ga[jt][2] + gb[jt]), sigmoidf_(ga[jt][3] + gb[jt]));
      }
    }
  }

  // ---- Phase B3: V -> R2 LDS [ch][ii] (wave = (chq, vih)) ----
  {
    const int chq = w8 & 3, vih = w8 >> 2;
    bf16x8 bfv[2][4];
    float vb[2];
    #pragma unroll
    for (int jt = 0; jt < 2; ++jt) {
      #pragma unroll
      for (int kt = 0; kt < 4; ++kt)
        bfv[jt][kt] = *reinterpret_cast<const bf16x8*>(
            &wvT[(size_t)(chq * 32 + jt * 16 + lr) * 128 + kt * 32 + lg * 8]);
      vb[jt] = bv[chq * 32 + jt * 16 + lr];
    }
    #pragma unroll 1
    for (int it = 0; it < 8; ++it) {
      bf16x8 af[4];
      #pragma unroll
      for (int kt = 0; kt < 4; ++kt) {
        const int i = vih * 128 + it * 16 + lr;
        int byte = i * 256 + (kt * 64 + lg * 16);
        byte ^= ((i & 15) << 4);
        af[kt] = *reinterpret_cast<const bf16x8*>(zkb + byte);
      }
      f32x4 va[2];
      va[0] = (f32x4){0.f, 0.f, 0.f, 0.f};
      va[1] = (f32x4){0.f, 0.f, 0.f, 0.f};
      #pragma unroll
      for (int kt = 0; kt < 4; ++kt)
        #pragma unroll
        for (int jt = 0; jt < 2; ++jt)
          va[jt] = __builtin_amdgcn_mfma_f32_16x16x32_bf16(af[kt], bfv[jt][kt], va[jt], 0, 0, 0);
      const int ii0 = vih * 128 + it * 16 + lg * 4;
      #pragma unroll
      for (int jt = 0; jt < 2; ++jt) {
        const int ch = chq * 32 + jt * 16 + lr;
        uint2 pv;
        pv.x = cvtpk(va[jt][0] + vb[jt], va[jt][1] + vb[jt]);
        pv.y = cvtpk(va[jt][2] + vb[jt], va[jt][3] + vb[jt]);
        int byte = ch * 512 + ii0 * 2;
        byte ^= ((ch & 7) << 4);
        *reinterpret_cast<uint2*>(vtb + byte) = pv;
      }
    }
  }

  // ---- Phase C: K over R1 in place, 4 chunks of 64 rows (wave = jt w8) ----
  {
    bf16x8 bfk[4];
    #pragma unroll
    for (int kt = 0; kt < 4; ++kt)
      bfk[kt] = *reinterpret_cast<const bf16x8*>(
          &wkT[(size_t)(w8 * 16 + lr) * 128 + kt * 32 + lg * 8]);
    const float4 kb4 = *reinterpret_cast<const float4*>(&bk[w8 * 16 + lg * 4]);
    const float kb[4] = {kb4.x, kb4.y, kb4.z, kb4.w};

    #pragma unroll 1
    for (int c = 0; c < 4; ++c) {
      bf16x8 afr[4][4];
      #pragma unroll
      for (int itc = 0; itc < 4; ++itc)
        #pragma unroll
        for (int kt = 0; kt < 4; ++kt) {
          const int i = c * 64 + itc * 16 + lr;
          int byte = i * 256 + (kt * 64 + lg * 16);
          byte ^= ((i & 15) << 4);
          afr[itc][kt] = *reinterpret_cast<const bf16x8*>(zkb + byte);
        }
      __syncthreads();   // all reads of these rows done (all waves)
      #pragma unroll
      for (int itc = 0; itc < 4; ++itc) {
        f32x4 ka = (f32x4){0.f, 0.f, 0.f, 0.f};
        #pragma unroll
        for (int kt = 0; kt < 4; ++kt)
          ka = __builtin_amdgcn_mfma_f32_16x16x32_bf16(bfk[kt], afr[itc][kt], ka, 0, 0, 0);
        const int j = c * 64 + itc * 16 + lr;
        uint2 pkk;
        pkk.x = cvtpk(ka[0] + kb[0], ka[1] + kb[1]);
        pkk.y = cvtpk(ka[2] + kb[2], ka[3] + kb[3]);
        int byte = j * 256 + (w8 * 16 + lg * 4) * 2;
        byte ^= ((j & 15) << 4);
        *reinterpret_cast<uint2*>(zkb + byte) = pkk;
      }
      __syncthreads();   // K rows visible before next chunk / attention
    }
  }

  // ---- Phase D: attention per (h, ihalf); og kept in ogpk regs ----
  unsigned ogpk[8][4];
  #pragma unroll
  for (int it = 0; it < 8; ++it) {
    // ---- S^T = K · Q^T over all 256 keys ----
    f32x4 sacc[16];
    #pragma unroll
    for (int jt = 0; jt < 16; ++jt) sacc[jt] = (f32x4){0.f, 0.f, 0.f, 0.f};
    #pragma unroll
    for (int jt = 0; jt < 16; ++jt) {
      const int j = jt * 16 + lr;
      int byte = j * 256 + h * 64 + lg * 16;
      byte ^= ((j & 15) << 4);
      bf16x8 kf = *reinterpret_cast<const bf16x8*>(zkb + byte);
      sacc[jt] = __builtin_amdgcn_mfma_f32_16x16x32_bf16(kf, qfrag[it], sacc[jt], 0, 0, 0);
    }

    // ---- max-free softmax: exp in place; normalization deferred past PV ----
    float psum = 0.f;
    #pragma unroll
    for (int jt = 0; jt < 16; ++jt)
      #pragma unroll
      for (int r = 0; r < 4; ++r) {
        const float e = __expf(sacc[jt][r]);
        sacc[jt][r] = e;
        psum += e;
      }
    psum += __shfl_xor(psum, 16);
    psum += __shfl_xor(psum, 32);
    const float rl = 1.0f / psum;

    // ---- PV in 4 quarter rounds (2KB/wave P buffer), unnormalized P ----
    f32x4 oacc[2];
    oacc[0] = (f32x4){0.f, 0.f, 0.f, 0.f};
    oacc[1] = (f32x4){0.f, 0.f, 0.f, 0.f};
    #pragma unroll
    for (int qr = 0; qr < 4; ++qr) {
      #pragma unroll
      for (int jj = 0; jj < 4; ++jj) {
        const int jt = qr * 4 + jj;
        uint2 pk;
        pk.x = cvtpk(sacc[jt][0], sacc[jt][1]);
        pk.y = cvtpk(sacc[jt][2], sacc[jt][3]);
        int byte = lr * 128 + (jj * 16 + lg * 4) * 2;
        byte ^= ((lr & 7) << 4);
        *reinterpret_cast<uint2*>(plb + byte) = pk;
      }
      asm volatile("s_waitcnt lgkmcnt(0)" ::: "memory");
      __builtin_amdgcn_sched_barrier(0);
      #pragma unroll
      for (int kq = 0; kq < 2; ++kq) {
        int pbyte = lr * 128 + (kq * 64 + lg * 16);
        pbyte ^= ((lr & 7) << 4);
        bf16x8 pf = *reinterpret_cast<const bf16x8*>(plb + pbyte);
        #pragma unroll
        for (int cht = 0; cht < 2; ++cht) {
          const int ch = h * 32 + cht * 16 + lr;
          int vbyte = ch * 512 + (qr * 128 + kq * 64 + lg * 16);
          vbyte ^= ((ch & 7) << 4);
          bf16x8 vf = *reinterpret_cast<const bf16x8*>(vtb + vbyte);
          oacc[cht] = __builtin_amdgcn_mfma_f32_16x16x32_bf16(pf, vf, oacc[cht], 0, 0, 0);
        }
      }
    }

    // row-sum across the 4 lane-groups sharing a row
    {
      // gate (from regs) + deferred normalize -> packed og registers
      #pragma unroll
      for (int cht = 0; cht < 2; ++cht)
        #pragma unroll
        for (int rp = 0; rp < 2; ++rp) {
          const float g0 = bf2f((unsigned short)(gpk[it][cht][rp] & 0xffffu));
          const float g1 = bf2f((unsigned short)(gpk[it][cht][rp] >> 16));
          ogpk[it][cht * 2 + rp] = cvtpk(oacc[cht][rp * 2 + 0] * rl * g0,
                                         oacc[cht][rp * 2 + 1] * rl * g1);
        }
    }
  }

  // ---- og -> zkl LDS [pos][128ch] (K/V dead); swizzle (pos&15)<<4 ----
  __syncthreads();   // all waves done reading K (zkl) and V (vtl)
  #pragma unroll
  for (int it = 0; it < 8; ++it)
    #pragma unroll
    for (int cht = 0; cht < 2; ++cht)
      #pragma unroll
      for (int r = 0; r < 4; ++r) {
        const int pos = ihalf * 128 + it * 16 + lg * 4 + r;
        const int ch  = h * 32 + cht * 16 + lr;
        int byte = pos * 256 + ch * 2;
        byte ^= ((pos & 15) << 4);
        *reinterpret_cast<unsigned short*>(zkb + byte) =
            (unsigned short)(ogpk[it][cht * 2 + (r >> 1)] >> ((r & 1) * 16));
      }
  __syncthreads();   // og tile visible

  // ---- Phase E (fused K3): out^T = w2^T · og^T, og from LDS ----
  {
    const unsigned short* w2T = wT + 4 * (DZc * DHCc);
    bf16x8 zb[2][4];
    #pragma unroll
    for (int sub = 0; sub < 2; ++sub) {
      const int pos = w8 * 32 + sub * 16 + lr;
      #pragma unroll
      for (int kt = 0; kt < 4; ++kt) {
        int byte = pos * 256 + kt * 64 + lg * 16;
        byte ^= ((pos & 15) << 4);
        zb[sub][kt] = *reinterpret_cast<const bf16x8*>(zkb + byte);
      }
    }
    #pragma unroll
    for (int ct = 0; ct < 8; ++ct) {
      bf16x8 af[4];
      #pragma unroll
      for (int kt = 0; kt < 4; ++kt)
        af[kt] = *reinterpret_cast<const bf16x8*>(
            &w2T[(size_t)(ct * 16 + lr) * 128 + kt * 32 + lg * 8]);
      #pragma unroll
      for (int sub = 0; sub < 2; ++sub) {
        f32x4 acc = (f32x4){0.f, 0.f, 0.f, 0.f};
        #pragma unroll
        for (int kt = 0; kt < 4; ++kt)
          acc = __builtin_amdgcn_mfma_f32_16x16x32_bf16(af[kt], zb[sub][kt], acc, 0, 0, 0);
        const size_t gpos = (size_t)n * 256 + w8 * 32 + sub * 16 + lr;
        #pragma unroll
        for (int r = 0; r < 4; ++r) {
          const int c = ct * 16 + lg * 4 + r;
          out[(size_t)c * NPOSc + gpos] = acc[r] + b2[c];
        }
      }
    }
  }
}

// ---------------------------------------------------------------------------
extern "C" void kernel_launch(void* const* d_in, const int* in_sizes, int n_in,
                              void* d_out, int out_size, void* d_ws, size_t ws_size,
                              hipStream_t stream) {
  const float* z   = (const float*)d_in[0];
  const float* lnw = (const float*)d_in[1];
  const float* lnb = (const float*)d_in[2];
  const float* wq  = (const float*)d_in[3];
  const float* bq  = (const float*)d_in[4];
  const float* wk  = (const float*)d_in[5];
  const float* bk  = (const float*)d_in[6];
  const float* wv  = (const float*)d_in[7];
  const float* bv  = (const float*)d_in[8];
  const float* wg  = (const float*)d_in[9];
  const float* bg  = (const float*)d_in[10];
  const float* w2  = (const float*)d_in[11];
  const float* b2  = (const float*)d_in[12];
  float* out = (float*)d_out;

  unsigned short* wT = (unsigned short*)d_ws;   // 5 x 16384 bf16 weights

  prep_weights<<<5, 256, 0, stream>>>(wq, wk, wv, wg, w2, wT);
  fused_ln_proj_attn<<<Lc, 512, 0, stream>>>(
      z, lnw, lnb, wT, bq, bk, bv, bg, b2, out);
}

// Round 20
// 68.057 us; speedup vs baseline: 1.3738x; 1.0244x over previous
//
#include <hip/hip_runtime.h>
#include <cstdint>
#include <cstddef>

#define DZc   128
#define Lc    256
#define Hc    4
#define DCc   32
#define DHCc  128
#define NPOSc (Lc * Lc)

typedef __attribute__((ext_vector_type(8))) short bf16x8;
typedef __attribute__((ext_vector_type(4))) short bf16x4;
typedef __attribute__((ext_vector_type(4))) float f32x4;

static __device__ __forceinline__ unsigned short f2bf(float f) {
  unsigned u = __float_as_uint(f);
  u += 0x7FFFu + ((u >> 16) & 1u);     // round-to-nearest-even
  return (unsigned short)(u >> 16);
}
static __device__ __forceinline__ float bf2f(unsigned short h) {
  return __uint_as_float(((unsigned)h) << 16);
}
static __device__ __forceinline__ float sigmoidf_(float x) {
  return 1.0f / (1.0f + __expf(-x));
}
// HW packed f32->bf16 (RNE, bit-identical to f2bf): 1 instr instead of ~8.
static __device__ __forceinline__ unsigned cvtpk(float lo, float hi) {
  unsigned r;
  asm("v_cvt_pk_bf16_f32 %0, %1, %2" : "=v"(r) : "v"(lo), "v"(hi));
  return r;
}

// ---------------------------------------------------------------------------
// prep: weights fp32 [k][j] -> bf16 transposed [j][k]; q-scale folded into wq.
// slot 0..3 = wq,wk,wv,wg ; slot 4 = w2 (-> w2T[c][k]).
// ---------------------------------------------------------------------------
__global__ __launch_bounds__(256) void prep_weights(
    const float* __restrict__ wq, const float* __restrict__ wk,
    const float* __restrict__ wv, const float* __restrict__ wg,
    const float* __restrict__ w2, unsigned short* __restrict__ wT)
{
  const int b = blockIdx.x;  // 0..4
  const int t = threadIdx.x;
  const float* src = (b == 0) ? wq : (b == 1) ? wk : (b == 2) ? wv : (b == 3) ? wg : w2;
  unsigned short* dst = wT + (size_t)b * (DZc * DHCc);
  const float scale = (b == 0) ? 0.17677669529663687f : 1.0f;  // sqrt(1/32)
  for (int p = 0; p < 64; ++p) {
    const int idx = p * 256 + t;             // 16384 elements
    const int kk = idx >> 7, j = idx & 127;  // src[kk][j]
    dst[j * 128 + kk] = f2bf(src[idx] * scale);
  }
}

// ---------------------------------------------------------------------------
// FUSED kernel, R20 = R19 with two latency-bound fixes (R19 lesson: traffic
// cuts were neutral -> not BW-bound; 55% of cycles idle at 2 waves/SIMD):
//   1. K computed into REGISTERS during the projection phase (R17-proven):
//      8 barriers -> 2; all four projection GEMMs become one schedulable
//      region.
//   2. Phase D quarter-fused (R15-proven, full unroll): sacc 64->16 VGPRs
//      live; QK-MFMA / exp-VALU / PV-MFMA interleave across quarters.
// ---------------------------------------------------------------------------
__global__ __launch_bounds__(512, 2) void fused_ln_proj_attn(
    const float* __restrict__ z, const float* __restrict__ lnw, const float* __restrict__ lnb,
    const unsigned short* __restrict__ wT,
    const float* __restrict__ bq, const float* __restrict__ bk,
    const float* __restrict__ bv, const float* __restrict__ bg,
    const float* __restrict__ b2, float* __restrict__ out)
{
  __shared__ unsigned short zkl[Lc * DZc];     // 64 KB: zn -> K [j][128ch] -> og [pos][128ch]
  __shared__ unsigned short vtl[DHCc * Lc];    // 64 KB: V^T [ch][ii]
  __shared__ unsigned short pll[8][16 * 64];   // 16 KB: per-wave P quarter

  const int t  = threadIdx.x;
  const int n  = blockIdx.x;
  const int w8 = t >> 6;
  const int l  = t & 63;
  const int lr = l & 15;
  const int lg = l >> 4;
  const int h     = w8 & 3;      // head for q/g/attention
  const int ihalf = w8 >> 2;     // query-row half for q/g/attention

  char* zkb = reinterpret_cast<char*>(zkl);
  char* vtb = reinterpret_cast<char*>(vtl);
  char* plb = reinterpret_cast<char*>(&pll[w8][0]);

  // ---- Phase A: LN (in-register stats, 16-lane shfl tree), 2 passes ----
  #pragma unroll
  for (int p = 0; p < 2; ++p) {
    const int pq = t >> 4;          // 0..31 pos-quad
    const int cg = t & 15;          // 0..15 channel group (8 ch)
    const int gp = n * 256 + p * 128 + pq * 4;
    const int cbase = cg * 8;

    float4 zr[8];
    #pragma unroll
    for (int cc = 0; cc < 8; ++cc)
      zr[cc] = *reinterpret_cast<const float4*>(&z[(size_t)(cbase + cc) * NPOSc + gp]);

    float s[4] = {0.f, 0.f, 0.f, 0.f}, s2[4] = {0.f, 0.f, 0.f, 0.f};
    #pragma unroll
    for (int cc = 0; cc < 8; ++cc) {
      s[0] += zr[cc].x; s2[0] += zr[cc].x * zr[cc].x;
      s[1] += zr[cc].y; s2[1] += zr[cc].y * zr[cc].y;
      s[2] += zr[cc].z; s2[2] += zr[cc].z * zr[cc].z;
      s[3] += zr[cc].w; s2[3] += zr[cc].w * zr[cc].w;
    }
    #pragma unroll
    for (int m = 1; m <= 8; m <<= 1) {
      #pragma unroll
      for (int e = 0; e < 4; ++e) {
        s[e]  += __shfl_xor(s[e],  m);
        s2[e] += __shfl_xor(s2[e], m);
      }
    }
    float mu[4], rs[4];
    #pragma unroll
    for (int e = 0; e < 4; ++e) {
      mu[e] = s[e] * (1.0f / DZc);
      const float var = s2[e] * (1.0f / DZc) - mu[e] * mu[e];
      rs[e] = rsqrtf(var + 1e-5f);
    }
    float lw[8], lb[8];
    #pragma unroll
    for (int q4 = 0; q4 < 2; ++q4) {
      const float4 a = *reinterpret_cast<const float4*>(&lnw[cbase + q4 * 4]);
      const float4 b = *reinterpret_cast<const float4*>(&lnb[cbase + q4 * 4]);
      lw[q4 * 4 + 0] = a.x; lw[q4 * 4 + 1] = a.y; lw[q4 * 4 + 2] = a.z; lw[q4 * 4 + 3] = a.w;
      lb[q4 * 4 + 0] = b.x; lb[q4 * 4 + 1] = b.y; lb[q4 * 4 + 2] = b.z; lb[q4 * 4 + 3] = b.w;
    }
    #pragma unroll
    for (int e = 0; e < 4; ++e) {
      const int i = p * 128 + pq * 4 + e;
      float zn[8];
      #pragma unroll
      for (int cc = 0; cc < 8; ++cc) {
        const float zc = (e == 0) ? zr[cc].x : (e == 1) ? zr[cc].y
                       : (e == 2) ? zr[cc].z : zr[cc].w;
        zn[cc] = (zc - mu[e]) * rs[e] * lw[cc] + lb[cc];
      }
      uint4 pw;
      pw.x = cvtpk(zn[0], zn[1]); pw.y = cvtpk(zn[2], zn[3]);
      pw.z = cvtpk(zn[4], zn[5]); pw.w = cvtpk(zn[6], zn[7]);
      int byte = i * 256 + cbase * 2;
      byte ^= ((i & 15) << 4);
      *reinterpret_cast<uint4*>(zkb + byte) = pw;
    }
  }
  __syncthreads();

  const unsigned short* wqT = wT;
  const unsigned short* wkT = wT + 1 * (DZc * DHCc);
  const unsigned short* wvT = wT + 2 * (DZc * DHCc);
  const unsigned short* wgT = wT + 3 * (DZc * DHCc);

  // ---- Phase B1: q -> qfrag[8] regs (attn B-frag layout) ----
  bf16x8 qfrag[8];
  {
    bf16x8 bfq[2][4];
    float4 qb4[2];
    #pragma unroll
    for (int jt = 0; jt < 2; ++jt) {
      #pragma unroll
      for (int kt = 0; kt < 4; ++kt)
        bfq[jt][kt] = *reinterpret_cast<const bf16x8*>(
            &wqT[(size_t)(h * 32 + jt * 16 + lr) * 128 + kt * 32 + lg * 8]);
      qb4[jt] = *reinterpret_cast<const float4*>(&bq[h * 32 + jt * 16 + lg * 4]);
      qb4[jt].x *= 0.17677669529663687f; qb4[jt].y *= 0.17677669529663687f;
      qb4[jt].z *= 0.17677669529663687f; qb4[jt].w *= 0.17677669529663687f;
    }
    #pragma unroll
    for (int it = 0; it < 8; ++it) {
      bf16x8 af[4];
      #pragma unroll
      for (int kt = 0; kt < 4; ++kt) {
        const int i = ihalf * 128 + it * 16 + lr;
        int byte = i * 256 + (kt * 64 + lg * 16);
        byte ^= ((i & 15) << 4);
        af[kt] = *reinterpret_cast<const bf16x8*>(zkb + byte);
      }
      f32x4 qa[2];
      qa[0] = (f32x4){0.f, 0.f, 0.f, 0.f};
      qa[1] = (f32x4){0.f, 0.f, 0.f, 0.f};
      #pragma unroll
      for (int kt = 0; kt < 4; ++kt)
        #pragma unroll
        for (int jt = 0; jt < 2; ++jt)
          qa[jt] = __builtin_amdgcn_mfma_f32_16x16x32_bf16(bfq[jt][kt], af[kt], qa[jt], 0, 0, 0);
      // srcw[jt][w]: ch = h*32 + jt*16 + lg*4 + 2w+{0,1}, pos = lr
      unsigned srcw0[2], srcw1[2];
      srcw0[0] = cvtpk(qa[0][0] + qb4[0].x, qa[0][1] + qb4[0].y);
      srcw0[1] = cvtpk(qa[0][2] + qb4[0].z, qa[0][3] + qb4[0].w);
      srcw1[0] = cvtpk(qa[1][0] + qb4[1].x, qa[1][1] + qb4[1].y);
      srcw1[1] = cvtpk(qa[1][2] + qb4[1].z, qa[1][3] + qb4[1].w);
      // shuffle to qfrag: lane wants row lr, ch octet lg*8 (quad 2lg, 2lg+1)
      unsigned qw[4];
      #pragma unroll
      for (int i4 = 0; i4 < 4; ++i4) {
        const int quad = lg * 2 + (i4 >> 1);
        const int srcl = (quad & 3) * 16 + lr;
        const unsigned a = (unsigned)__shfl((int)srcw0[i4 & 1], srcl);
        const unsigned b = (unsigned)__shfl((int)srcw1[i4 & 1], srcl);
        qw[i4] = (lg >= 2) ? b : a;   // jt_src = quad>>2 == (lg>=2)
      }
      uint4 qv; qv.x = qw[0]; qv.y = qw[1]; qv.z = qw[2]; qv.w = qw[3];
      qfrag[it] = *reinterpret_cast<const bf16x8*>(&qv);
    }
  }

  // ---- Phase B2: g -> gpk[8][2][2] packed regs (O lane layout) ----
  unsigned gpk[8][2][2];
  {
    bf16x8 bfg[2][4];
    float gb[2];
    #pragma unroll
    for (int jt = 0; jt < 2; ++jt) {
      #pragma unroll
      for (int kt = 0; kt < 4; ++kt)
        bfg[jt][kt] = *reinterpret_cast<const bf16x8*>(
            &wgT[(size_t)(h * 32 + jt * 16 + lr) * 128 + kt * 32 + lg * 8]);
      gb[jt] = bg[h * 32 + jt * 16 + lr];
    }
    #pragma unroll
    for (int it = 0; it < 8; ++it) {
      bf16x8 af[4];
      #pragma unroll
      for (int kt = 0; kt < 4; ++kt) {
        const int i = ihalf * 128 + it * 16 + lr;
        int byte = i * 256 + (kt * 64 + lg * 16);
        byte ^= ((i & 15) << 4);
        af[kt] = *reinterpret_cast<const bf16x8*>(zkb + byte);
      }
      f32x4 ga[2];
      ga[0] = (f32x4){0.f, 0.f, 0.f, 0.f};
      ga[1] = (f32x4){0.f, 0.f, 0.f, 0.f};
      #pragma unroll
      for (int kt = 0; kt < 4; ++kt)
        #pragma unroll
        for (int jt = 0; jt < 2; ++jt)
          ga[jt] = __builtin_amdgcn_mfma_f32_16x16x32_bf16(af[kt], bfg[jt][kt], ga[jt], 0, 0, 0);
      #pragma unroll
      for (int jt = 0; jt < 2; ++jt) {
        gpk[it][jt][0] = cvtpk(sigmoidf_(ga[jt][0] + gb[jt]), sigmoidf_(ga[jt][1] + gb[jt]));
        gpk[it][jt][1] = cvtpk(sigmoidf_(ga[jt][2] + gb[jt]), sigmoidf_(ga[jt][3] + gb[jt]));
      }
    }
  }

  // ---- Phase B3: V -> R2 LDS [ch][ii] (wave = (chq, vih)) ----
  {
    const int chq = w8 & 3, vih = w8 >> 2;
    bf16x8 bfv[2][4];
    float vb[2];
    #pragma unroll
    for (int jt = 0; jt < 2; ++jt) {
      #pragma unroll
      for (int kt = 0; kt < 4; ++kt)
        bfv[jt][kt] = *reinterpret_cast<const bf16x8*>(
            &wvT[(size_t)(chq * 32 + jt * 16 + lr) * 128 + kt * 32 + lg * 8]);
      vb[jt] = bv[chq * 32 + jt * 16 + lr];
    }
    #pragma unroll 1
    for (int it = 0; it < 8; ++it) {
      bf16x8 af[4];
      #pragma unroll
      for (int kt = 0; kt < 4; ++kt) {
        const int i = vih * 128 + it * 16 + lr;
        int byte = i * 256 + (kt * 64 + lg * 16);
        byte ^= ((i & 15) << 4);
        af[kt] = *reinterpret_cast<const bf16x8*>(zkb + byte);
      }
      f32x4 va[2];
      va[0] = (f32x4){0.f, 0.f, 0.f, 0.f};
      va[1] = (f32x4){0.f, 0.f, 0.f, 0.f};
      #pragma unroll
      for (int kt = 0; kt < 4; ++kt)
        #pragma unroll
        for (int jt = 0; jt < 2; ++jt)
          va[jt] = __builtin_amdgcn_mfma_f32_16x16x32_bf16(af[kt], bfv[jt][kt], va[jt], 0, 0, 0);
      const int ii0 = vih * 128 + it * 16 + lg * 4;
      #pragma unroll
      for (int jt = 0; jt < 2; ++jt) {
        const int ch = chq * 32 + jt * 16 + lr;
        uint2 pv;
        pv.x = cvtpk(va[jt][0] + vb[jt], va[jt][1] + vb[jt]);
        pv.y = cvtpk(va[jt][2] + vb[jt], va[jt][3] + vb[jt]);
        int byte = ch * 512 + ii0 * 2;
        byte ^= ((ch & 7) << 4);
        *reinterpret_cast<uint2*>(vtb + byte) = pv;
      }
    }
  }

  // ---- Phase B4: K -> kreg[16] (wave owns 16 K-channels, all 256 rows) ----
  uint2 kreg[16];
  {
    bf16x8 bfk[4];
    #pragma unroll
    for (int kt = 0; kt < 4; ++kt)
      bfk[kt] = *reinterpret_cast<const bf16x8*>(
          &wkT[(size_t)(w8 * 16 + lr) * 128 + kt * 32 + lg * 8]);
    const float4 kb4 = *reinterpret_cast<const float4*>(&bk[w8 * 16 + lg * 4]);
    const float kb[4] = {kb4.x, kb4.y, kb4.z, kb4.w};

    #pragma unroll
    for (int itt = 0; itt < 16; ++itt) {
      bf16x8 af[4];
      #pragma unroll
      for (int kt = 0; kt < 4; ++kt) {
        const int i = itt * 16 + lr;
        int byte = i * 256 + (kt * 64 + lg * 16);
        byte ^= ((i & 15) << 4);
        af[kt] = *reinterpret_cast<const bf16x8*>(zkb + byte);
      }
      f32x4 ka = (f32x4){0.f, 0.f, 0.f, 0.f};
      #pragma unroll
      for (int kt = 0; kt < 4; ++kt)
        ka = __builtin_amdgcn_mfma_f32_16x16x32_bf16(bfk[kt], af[kt], ka, 0, 0, 0);
      kreg[itt].x = cvtpk(ka[0] + kb[0], ka[1] + kb[1]);
      kreg[itt].y = cvtpk(ka[2] + kb[2], ka[3] + kb[3]);
    }
  }
  __syncthreads();   // ALL zn reads (B1,B2,B3,B4, all waves) complete

  // ---- Phase C: write K over zn: [j][128ch], swizzle (j&15)<<4 ----
  #pragma unroll
  for (int itt = 0; itt < 16; ++itt) {
    const int j = itt * 16 + lr;
    int byte = j * 256 + (w8 * 16 + lg * 4) * 2;
    byte ^= ((j & 15) << 4);
    *reinterpret_cast<uint2*>(zkb + byte) = kreg[itt];
  }
  __syncthreads();   // K visible

  // ---- Phase D: attention per (h, ihalf); QUARTER-FUSED; og -> regs ----
  unsigned ogpk[8][4];
  #pragma unroll
  for (int it = 0; it < 8; ++it) {
    float psum = 0.f;
    f32x4 oacc[2];
    oacc[0] = (f32x4){0.f, 0.f, 0.f, 0.f};
    oacc[1] = (f32x4){0.f, 0.f, 0.f, 0.f};

    #pragma unroll
    for (int qr = 0; qr < 4; ++qr) {
      // QK^T for this quarter (4 j-tiles)
      f32x4 sacc[4];
      #pragma unroll
      for (int jj = 0; jj < 4; ++jj) sacc[jj] = (f32x4){0.f, 0.f, 0.f, 0.f};
      #pragma unroll
      for (int jj = 0; jj < 4; ++jj) {
        const int j = (qr * 4 + jj) * 16 + lr;
        int byte = j * 256 + h * 64 + lg * 16;
        byte ^= ((j & 15) << 4);
        bf16x8 kf = *reinterpret_cast<const bf16x8*>(zkb + byte);
        sacc[jj] = __builtin_amdgcn_mfma_f32_16x16x32_bf16(kf, qfrag[it], sacc[jj], 0, 0, 0);
      }
      // exp + psum (normalization deferred)
      #pragma unroll
      for (int jj = 0; jj < 4; ++jj)
        #pragma unroll
        for (int r = 0; r < 4; ++r) {
          const float e = __expf(sacc[jj][r]);
          sacc[jj][r] = e;
          psum += e;
        }
      // pack unnormalized P quarter
      #pragma unroll
      for (int jj = 0; jj < 4; ++jj) {
        uint2 pk;
        pk.x = cvtpk(sacc[jj][0], sacc[jj][1]);
        pk.y = cvtpk(sacc[jj][2], sacc[jj][3]);
        int byte = lr * 128 + (jj * 16 + lg * 4) * 2;
        byte ^= ((lr & 7) << 4);
        *reinterpret_cast<uint2*>(plb + byte) = pk;
      }
      asm volatile("s_waitcnt lgkmcnt(0)" ::: "memory");
      __builtin_amdgcn_sched_barrier(0);
      // PV for this quarter
      #pragma unroll
      for (int kq = 0; kq < 2; ++kq) {
        int pbyte = lr * 128 + (kq * 64 + lg * 16);
        pbyte ^= ((lr & 7) << 4);
        bf16x8 pf = *reinterpret_cast<const bf16x8*>(plb + pbyte);
        #pragma unroll
        for (int cht = 0; cht < 2; ++cht) {
          const int ch = h * 32 + cht * 16 + lr;
          int vbyte = ch * 512 + (qr * 128 + kq * 64 + lg * 16);
          vbyte ^= ((ch & 7) << 4);
          bf16x8 vf = *reinterpret_cast<const bf16x8*>(vtb + vbyte);
          oacc[cht] = __builtin_amdgcn_mfma_f32_16x16x32_bf16(pf, vf, oacc[cht], 0, 0, 0);
        }
      }
    }

    // row-sum across the 4 lane-groups sharing a row
    psum += __shfl_xor(psum, 16);
    psum += __shfl_xor(psum, 32);
    const float rl = 1.0f / psum;

    // gate (from regs) + deferred normalize -> packed og registers
    #pragma unroll
    for (int cht = 0; cht < 2; ++cht)
      #pragma unroll
      for (int rp = 0; rp < 2; ++rp) {
        const float g0 = bf2f((unsigned short)(gpk[it][cht][rp] & 0xffffu));
        const float g1 = bf2f((unsigned short)(gpk[it][cht][rp] >> 16));
        ogpk[it][cht * 2 + rp] = cvtpk(oacc[cht][rp * 2 + 0] * rl * g0,
                                       oacc[cht][rp * 2 + 1] * rl * g1);
      }
  }

  // ---- og -> zkl LDS [pos][128ch] (K/V dead); swizzle (pos&15)<<4 ----
  __syncthreads();   // all waves done reading K (zkl) and V (vtl)
  #pragma unroll
  for (int it = 0; it < 8; ++it)
    #pragma unroll
    for (int cht = 0; cht < 2; ++cht)
      #pragma unroll
      for (int r = 0; r < 4; ++r) {
        const int pos = ihalf * 128 + it * 16 + lg * 4 + r;
        const int ch  = h * 32 + cht * 16 + lr;
        int byte = pos * 256 + ch * 2;
        byte ^= ((pos & 15) << 4);
        *reinterpret_cast<unsigned short*>(zkb + byte) =
            (unsigned short)(ogpk[it][cht * 2 + (r >> 1)] >> ((r & 1) * 16));
      }
  __syncthreads();   // og tile visible

  // ---- Phase E (fused K3): out^T = w2^T · og^T, og from LDS ----
  {
    const unsigned short* w2T = wT + 4 * (DZc * DHCc);
    bf16x8 zb[2][4];
    #pragma unroll
    for (int sub = 0; sub < 2; ++sub) {
      const int pos = w8 * 32 + sub * 16 + lr;
      #pragma unroll
      for (int kt = 0; kt < 4; ++kt) {
        int byte = pos * 256 + kt * 64 + lg * 16;
        byte ^= ((pos & 15) << 4);
        zb[sub][kt] = *reinterpret_cast<const bf16x8*>(zkb + byte);
      }
    }
    #pragma unroll
    for (int ct = 0; ct < 8; ++ct) {
      bf16x8 af[4];
      #pragma unroll
      for (int kt = 0; kt < 4; ++kt)
        af[kt] = *reinterpret_cast<const bf16x8*>(
            &w2T[(size_t)(ct * 16 + lr) * 128 + kt * 32 + lg * 8]);
      #pragma unroll
      for (int sub = 0; sub < 2; ++sub) {
        f32x4 acc = (f32x4){0.f, 0.f, 0.f, 0.f};
        #pragma unroll
        for (int kt = 0; kt < 4; ++kt)
          acc = __builtin_amdgcn_mfma_f32_16x16x32_bf16(af[kt], zb[sub][kt], acc, 0, 0, 0);
        const size_t gpos = (size_t)n * 256 + w8 * 32 + sub * 16 + lr;
        #pragma unroll
        for (int r = 0; r < 4; ++r) {
          const int c = ct * 16 + lg * 4 + r;
          out[(size_t)c * NPOSc + gpos] = acc[r] + b2[c];
        }
      }
    }
  }
}

// ---------------------------------------------------------------------------
extern "C" void kernel_launch(void* const* d_in, const int* in_sizes, int n_in,
                              void* d_out, int out_size, void* d_ws, size_t ws_size,
                              hipStream_t stream) {
  const float* z   = (const float*)d_in[0];
  const float* lnw = (const float*)d_in[1];
  const float* lnb = (const float*)d_in[2];
  const float* wq  = (const float*)d_in[3];
  const float* bq  = (const float*)d_in[4];
  const float* wk  = (const float*)d_in[5];
  const float* bk  = (const float*)d_in[6];
  const float* wv  = (const float*)d_in[7];
  const float* bv  = (const float*)d_in[8];
  const float* wg  = (const float*)d_in[9];
  const float* bg  = (const float*)d_in[10];
  const float* w2  = (const float*)d_in[11];
  const float* b2  = (const float*)d_in[12];
  float* out = (float*)d_out;

  unsigned short* wT = (unsigned short*)d_ws;   // 5 x 16384 bf16 weights

  prep_weights<<<5, 256, 0, stream>>>(wq, wk, wv, wg, w2, wT);
  fused_ln_proj_attn<<<Lc, 512, 0, stream>>>(
      z, lnw, lnb, wT, bq, bk, bv, bg, b2, out);
}

// Round 23
// 67.525 us; speedup vs baseline: 1.3846x; 1.0079x over previous
//
#include <hip/hip_runtime.h>
#include <cstdint>
#include <cstddef>

#define DZc   128
#define Lc    256
#define Hc    4
#define DCc   32
#define DHCc  128
#define NPOSc (Lc * Lc)

typedef __attribute__((ext_vector_type(8))) short bf16x8;
typedef __attribute__((ext_vector_type(4))) short bf16x4;
typedef __attribute__((ext_vector_type(4))) float f32x4;

static __device__ __forceinline__ unsigned short f2bf(float f) {
  unsigned u = __float_as_uint(f);
  u += 0x7FFFu + ((u >> 16) & 1u);     // round-to-nearest-even
  return (unsigned short)(u >> 16);
}
static __device__ __forceinline__ float bf2f(unsigned short h) {
  return __uint_as_float(((unsigned)h) << 16);
}
static __device__ __forceinline__ float sigmoidf_(float x) {
  return 1.0f / (1.0f + __expf(-x));
}
// HW packed f32->bf16 (RNE, bit-identical to f2bf): 1 instr instead of ~8.
static __device__ __forceinline__ unsigned cvtpk(float lo, float hi) {
  unsigned r;
  asm("v_cvt_pk_bf16_f32 %0, %1, %2" : "=v"(r) : "v"(lo), "v"(hi));
  return r;
}

// ---------------------------------------------------------------------------
// prep: weights fp32 [k][j] -> bf16 transposed [j][k]; q-scale folded into wq.
// slot 0..3 = wq,wk,wv,wg ; slot 4 = w2 (-> w2T[c][k]).
// ---------------------------------------------------------------------------
__global__ __launch_bounds__(256) void prep_weights(
    const float* __restrict__ wq, const float* __restrict__ wk,
    const float* __restrict__ wv, const float* __restrict__ wg,
    const float* __restrict__ w2, unsigned short* __restrict__ wT)
{
  const int b = blockIdx.x;  // 0..4
  const int t = threadIdx.x;
  const float* src = (b == 0) ? wq : (b == 1) ? wk : (b == 2) ? wv : (b == 3) ? wg : w2;
  unsigned short* dst = wT + (size_t)b * (DZc * DHCc);
  const float scale = (b == 0) ? 0.17677669529663687f : 1.0f;  // sqrt(1/32)
  for (int p = 0; p < 64; ++p) {
    const int idx = p * 256 + t;             // 16384 elements
    const int kk = idx >> 7, j = idx & 127;  // src[kk][j]
    dst[j * 128 + kk] = f2bf(src[idx] * scale);
  }
}

// ---------------------------------------------------------------------------
// FUSED kernel (R23 = R20 verbatim, the best verified configuration):
//   A: LN in-register stats; zn bf16 -> LDS (swizzled)
//   B1/B2: q,g -> registers (one MFMA pass each; q in attn-B-frag layout)
//   B3: V -> LDS [ch][ii]; B4: K -> registers (all 256 rows)
//   C: K written over zn (2 barriers total)
//   D: quarter-fused QK^T -> exp -> pack -> PV; deferred normalization;
//      gate from registers; og packed into registers
//   og -> LDS; E: out-projection from LDS; fp32 out stores.
//   R21/R22 numerics bundle (exp2/L2E/rcp/setprio) REVERTED: deterministic
//   identical-absmax failures (1.77e-2) across two different exp codegens
//   -> logic interaction not isolated; restoring verified 68.06 us kernel.
// ---------------------------------------------------------------------------
__global__ __launch_bounds__(512, 2) void fused_ln_proj_attn(
    const float* __restrict__ z, const float* __restrict__ lnw, const float* __restrict__ lnb,
    const unsigned short* __restrict__ wT,
    const float* __restrict__ bq, const float* __restrict__ bk,
    const float* __restrict__ bv, const float* __restrict__ bg,
    const float* __restrict__ b2, float* __restrict__ out)
{
  __shared__ unsigned short zkl[Lc * DZc];     // 64 KB: zn -> K [j][128ch] -> og [pos][128ch]
  __shared__ unsigned short vtl[DHCc * Lc];    // 64 KB: V^T [ch][ii]
  __shared__ unsigned short pll[8][16 * 64];   // 16 KB: per-wave P quarter

  const int t  = threadIdx.x;
  const int n  = blockIdx.x;
  const int w8 = t >> 6;
  const int l  = t & 63;
  const int lr = l & 15;
  const int lg = l >> 4;
  const int h     = w8 & 3;      // head for q/g/attention
  const int ihalf = w8 >> 2;     // query-row half for q/g/attention

  char* zkb = reinterpret_cast<char*>(zkl);
  char* vtb = reinterpret_cast<char*>(vtl);
  char* plb = reinterpret_cast<char*>(&pll[w8][0]);

  // ---- Phase A: LN (in-register stats, 16-lane shfl tree), 2 passes ----
  #pragma unroll
  for (int p = 0; p < 2; ++p) {
    const int pq = t >> 4;          // 0..31 pos-quad
    const int cg = t & 15;          // 0..15 channel group (8 ch)
    const int gp = n * 256 + p * 128 + pq * 4;
    const int cbase = cg * 8;

    float4 zr[8];
    #pragma unroll
    for (int cc = 0; cc < 8; ++cc)
      zr[cc] = *reinterpret_cast<const float4*>(&z[(size_t)(cbase + cc) * NPOSc + gp]);

    float s[4] = {0.f, 0.f, 0.f, 0.f}, s2[4] = {0.f, 0.f, 0.f, 0.f};
    #pragma unroll
    for (int cc = 0; cc < 8; ++cc) {
      s[0] += zr[cc].x; s2[0] += zr[cc].x * zr[cc].x;
      s[1] += zr[cc].y; s2[1] += zr[cc].y * zr[cc].y;
      s[2] += zr[cc].z; s2[2] += zr[cc].z * zr[cc].z;
      s[3] += zr[cc].w; s2[3] += zr[cc].w * zr[cc].w;
    }
    #pragma unroll
    for (int m = 1; m <= 8; m <<= 1) {
      #pragma unroll
      for (int e = 0; e < 4; ++e) {
        s[e]  += __shfl_xor(s[e],  m);
        s2[e] += __shfl_xor(s2[e], m);
      }
    }
    float mu[4], rs[4];
    #pragma unroll
    for (int e = 0; e < 4; ++e) {
      mu[e] = s[e] * (1.0f / DZc);
      const float var = s2[e] * (1.0f / DZc) - mu[e] * mu[e];
      rs[e] = rsqrtf(var + 1e-5f);
    }
    float lw[8], lb[8];
    #pragma unroll
    for (int q4 = 0; q4 < 2; ++q4) {
      const float4 a = *reinterpret_cast<const float4*>(&lnw[cbase + q4 * 4]);
      const float4 b = *reinterpret_cast<const float4*>(&lnb[cbase + q4 * 4]);
      lw[q4 * 4 + 0] = a.x; lw[q4 * 4 + 1] = a.y; lw[q4 * 4 + 2] = a.z; lw[q4 * 4 + 3] = a.w;
      lb[q4 * 4 + 0] = b.x; lb[q4 * 4 + 1] = b.y; lb[q4 * 4 + 2] = b.z; lb[q4 * 4 + 3] = b.w;
    }
    #pragma unroll
    for (int e = 0; e < 4; ++e) {
      const int i = p * 128 + pq * 4 + e;
      float zn[8];
      #pragma unroll
      for (int cc = 0; cc < 8; ++cc) {
        const float zc = (e == 0) ? zr[cc].x : (e == 1) ? zr[cc].y
                       : (e == 2) ? zr[cc].z : zr[cc].w;
        zn[cc] = (zc - mu[e]) * rs[e] * lw[cc] + lb[cc];
      }
      uint4 pw;
      pw.x = cvtpk(zn[0], zn[1]); pw.y = cvtpk(zn[2], zn[3]);
      pw.z = cvtpk(zn[4], zn[5]); pw.w = cvtpk(zn[6], zn[7]);
      int byte = i * 256 + cbase * 2;
      byte ^= ((i & 15) << 4);
      *reinterpret_cast<uint4*>(zkb + byte) = pw;
    }
  }
  __syncthreads();

  const unsigned short* wqT = wT;
  const unsigned short* wkT = wT + 1 * (DZc * DHCc);
  const unsigned short* wvT = wT + 2 * (DZc * DHCc);
  const unsigned short* wgT = wT + 3 * (DZc * DHCc);

  // ---- Phase B1: q -> qfrag[8] regs (attn B-frag layout) ----
  bf16x8 qfrag[8];
  {
    bf16x8 bfq[2][4];
    float4 qb4[2];
    #pragma unroll
    for (int jt = 0; jt < 2; ++jt) {
      #pragma unroll
      for (int kt = 0; kt < 4; ++kt)
        bfq[jt][kt] = *reinterpret_cast<const bf16x8*>(
            &wqT[(size_t)(h * 32 + jt * 16 + lr) * 128 + kt * 32 + lg * 8]);
      qb4[jt] = *reinterpret_cast<const float4*>(&bq[h * 32 + jt * 16 + lg * 4]);
      qb4[jt].x *= 0.17677669529663687f; qb4[jt].y *= 0.17677669529663687f;
      qb4[jt].z *= 0.17677669529663687f; qb4[jt].w *= 0.17677669529663687f;
    }
    #pragma unroll
    for (int it = 0; it < 8; ++it) {
      bf16x8 af[4];
      #pragma unroll
      for (int kt = 0; kt < 4; ++kt) {
        const int i = ihalf * 128 + it * 16 + lr;
        int byte = i * 256 + (kt * 64 + lg * 16);
        byte ^= ((i & 15) << 4);
        af[kt] = *reinterpret_cast<const bf16x8*>(zkb + byte);
      }
      f32x4 qa[2];
      qa[0] = (f32x4){0.f, 0.f, 0.f, 0.f};
      qa[1] = (f32x4){0.f, 0.f, 0.f, 0.f};
      #pragma unroll
      for (int kt = 0; kt < 4; ++kt)
        #pragma unroll
        for (int jt = 0; jt < 2; ++jt)
          qa[jt] = __builtin_amdgcn_mfma_f32_16x16x32_bf16(bfq[jt][kt], af[kt], qa[jt], 0, 0, 0);
      // srcw[jt][w]: ch = h*32 + jt*16 + lg*4 + 2w+{0,1}, pos = lr
      unsigned srcw0[2], srcw1[2];
      srcw0[0] = cvtpk(qa[0][0] + qb4[0].x, qa[0][1] + qb4[0].y);
      srcw0[1] = cvtpk(qa[0][2] + qb4[0].z, qa[0][3] + qb4[0].w);
      srcw1[0] = cvtpk(qa[1][0] + qb4[1].x, qa[1][1] + qb4[1].y);
      srcw1[1] = cvtpk(qa[1][2] + qb4[1].z, qa[1][3] + qb4[1].w);
      // shuffle to qfrag: lane wants row lr, ch octet lg*8 (quad 2lg, 2lg+1)
      unsigned qw[4];
      #pragma unroll
      for (int i4 = 0; i4 < 4; ++i4) {
        const int quad = lg * 2 + (i4 >> 1);
        const int srcl = (quad & 3) * 16 + lr;
        const unsigned a = (unsigned)__shfl((int)srcw0[i4 & 1], srcl);
        const unsigned b = (unsigned)__shfl((int)srcw1[i4 & 1], srcl);
        qw[i4] = (lg >= 2) ? b : a;   // jt_src = quad>>2 == (lg>=2)
      }
      uint4 qv; qv.x = qw[0]; qv.y = qw[1]; qv.z = qw[2]; qv.w = qw[3];
      qfrag[it] = *reinterpret_cast<const bf16x8*>(&qv);
    }
  }

  // ---- Phase B2: g -> gpk[8][2][2] packed regs (O lane layout) ----
  unsigned gpk[8][2][2];
  {
    bf16x8 bfg[2][4];
    float gb[2];
    #pragma unroll
    for (int jt = 0; jt < 2; ++jt) {
      #pragma unroll
      for (int kt = 0; kt < 4; ++kt)
        bfg[jt][kt] = *reinterpret_cast<const bf16x8*>(
            &wgT[(size_t)(h * 32 + jt * 16 + lr) * 128 + kt * 32 + lg * 8]);
      gb[jt] = bg[h * 32 + jt * 16 + lr];
    }
    #pragma unroll
    for (int it = 0; it < 8; ++it) {
      bf16x8 af[4];
      #pragma unroll
      for (int kt = 0; kt < 4; ++kt) {
        const int i = ihalf * 128 + it * 16 + lr;
        int byte = i * 256 + (kt * 64 + lg * 16);
        byte ^= ((i & 15) << 4);
        af[kt] = *reinterpret_cast<const bf16x8*>(zkb + byte);
      }
      f32x4 ga[2];
      ga[0] = (f32x4){0.f, 0.f, 0.f, 0.f};
      ga[1] = (f32x4){0.f, 0.f, 0.f, 0.f};
      #pragma unroll
      for (int kt = 0; kt < 4; ++kt)
        #pragma unroll
        for (int jt = 0; jt < 2; ++jt)
          ga[jt] = __builtin_amdgcn_mfma_f32_16x16x32_bf16(af[kt], bfg[jt][kt], ga[jt], 0, 0, 0);
      #pragma unroll
      for (int jt = 0; jt < 2; ++jt) {
        gpk[it][jt][0] = cvtpk(sigmoidf_(ga[jt][0] + gb[jt]), sigmoidf_(ga[jt][1] + gb[jt]));
        gpk[it][jt][1] = cvtpk(sigmoidf_(ga[jt][2] + gb[jt]), sigmoidf_(ga[jt][3] + gb[jt]));
      }
    }
  }

  // ---- Phase B3: V -> R2 LDS [ch][ii] (wave = (chq, vih)) ----
  {
    const int chq = w8 & 3, vih = w8 >> 2;
    bf16x8 bfv[2][4];
    float vb[2];
    #pragma unroll
    for (int jt = 0; jt < 2; ++jt) {
      #pragma unroll
      for (int kt = 0; kt < 4; ++kt)
        bfv[jt][kt] = *reinterpret_cast<const bf16x8*>(
            &wvT[(size_t)(chq * 32 + jt * 16 + lr) * 128 + kt * 32 + lg * 8]);
      vb[jt] = bv[chq * 32 + jt * 16 + lr];
    }
    #pragma unroll 1
    for (int it = 0; it < 8; ++it) {
      bf16x8 af[4];
      #pragma unroll
      for (int kt = 0; kt < 4; ++kt) {
        const int i = vih * 128 + it * 16 + lr;
        int byte = i * 256 + (kt * 64 + lg * 16);
        byte ^= ((i & 15) << 4);
        af[kt] = *reinterpret_cast<const bf16x8*>(zkb + byte);
      }
      f32x4 va[2];
      va[0] = (f32x4){0.f, 0.f, 0.f, 0.f};
      va[1] = (f32x4){0.f, 0.f, 0.f, 0.f};
      #pragma unroll
      for (int kt = 0; kt < 4; ++kt)
        #pragma unroll
        for (int jt = 0; jt < 2; ++jt)
          va[jt] = __builtin_amdgcn_mfma_f32_16x16x32_bf16(af[kt], bfv[jt][kt], va[jt], 0, 0, 0);
      const int ii0 = vih * 128 + it * 16 + lg * 4;
      #pragma unroll
      for (int jt = 0; jt < 2; ++jt) {
        const int ch = chq * 32 + jt * 16 + lr;
        uint2 pv;
        pv.x = cvtpk(va[jt][0] + vb[jt], va[jt][1] + vb[jt]);
        pv.y = cvtpk(va[jt][2] + vb[jt], va[jt][3] + vb[jt]);
        int byte = ch * 512 + ii0 * 2;
        byte ^= ((ch & 7) << 4);
        *reinterpret_cast<uint2*>(vtb + byte) = pv;
      }
    }
  }

  // ---- Phase B4: K -> kreg[16] (wave owns 16 K-channels, all 256 rows) ----
  uint2 kreg[16];
  {
    bf16x8 bfk[4];
    #pragma unroll
    for (int kt = 0; kt < 4; ++kt)
      bfk[kt] = *reinterpret_cast<const bf16x8*>(
          &wkT[(size_t)(w8 * 16 + lr) * 128 + kt * 32 + lg * 8]);
    const float4 kb4 = *reinterpret_cast<const float4*>(&bk[w8 * 16 + lg * 4]);
    const float kb[4] = {kb4.x, kb4.y, kb4.z, kb4.w};

    #pragma unroll
    for (int itt = 0; itt < 16; ++itt) {
      bf16x8 af[4];
      #pragma unroll
      for (int kt = 0; kt < 4; ++kt) {
        const int i = itt * 16 + lr;
        int byte = i * 256 + (kt * 64 + lg * 16);
        byte ^= ((i & 15) << 4);
        af[kt] = *reinterpret_cast<const bf16x8*>(zkb + byte);
      }
      f32x4 ka = (f32x4){0.f, 0.f, 0.f, 0.f};
      #pragma unroll
      for (int kt = 0; kt < 4; ++kt)
        ka = __builtin_amdgcn_mfma_f32_16x16x32_bf16(bfk[kt], af[kt], ka, 0, 0, 0);
      kreg[itt].x = cvtpk(ka[0] + kb[0], ka[1] + kb[1]);
      kreg[itt].y = cvtpk(ka[2] + kb[2], ka[3] + kb[3]);
    }
  }
  __syncthreads();   // ALL zn reads (B1,B2,B3,B4, all waves) complete

  // ---- Phase C: write K over zn: [j][128ch], swizzle (j&15)<<4 ----
  #pragma unroll
  for (int itt = 0; itt < 16; ++itt) {
    const int j = itt * 16 + lr;
    int byte = j * 256 + (w8 * 16 + lg * 4) * 2;
    byte ^= ((j & 15) << 4);
    *reinterpret_cast<uint2*>(zkb + byte) = kreg[itt];
  }
  __syncthreads();   // K visible

  // ---- Phase D: attention per (h, ihalf); QUARTER-FUSED; og -> regs ----
  unsigned ogpk[8][4];
  #pragma unroll
  for (int it = 0; it < 8; ++it) {
    float psum = 0.f;
    f32x4 oacc[2];
    oacc[0] = (f32x4){0.f, 0.f, 0.f, 0.f};
    oacc[1] = (f32x4){0.f, 0.f, 0.f, 0.f};

    #pragma unroll
    for (int qr = 0; qr < 4; ++qr) {
      // QK^T for this quarter (4 j-tiles)
      f32x4 sacc[4];
      #pragma unroll
      for (int jj = 0; jj < 4; ++jj) sacc[jj] = (f32x4){0.f, 0.f, 0.f, 0.f};
      #pragma unroll
      for (int jj = 0; jj < 4; ++jj) {
        const int j = (qr * 4 + jj) * 16 + lr;
        int byte = j * 256 + h * 64 + lg * 16;
        byte ^= ((j & 15) << 4);
        bf16x8 kf = *reinterpret_cast<const bf16x8*>(zkb + byte);
        sacc[jj] = __builtin_amdgcn_mfma_f32_16x16x32_bf16(kf, qfrag[it], sacc[jj], 0, 0, 0);
      }
      // exp + psum (normalization deferred)
      #pragma unroll
      for (int jj = 0; jj < 4; ++jj)
        #pragma unroll
        for (int r = 0; r < 4; ++r) {
          const float e = __expf(sacc[jj][r]);
          sacc[jj][r] = e;
          psum += e;
        }
      // pack unnormalized P quarter
      #pragma unroll
      for (int jj = 0; jj < 4; ++jj) {
        uint2 pk;
        pk.x = cvtpk(sacc[jj][0], sacc[jj][1]);
        pk.y = cvtpk(sacc[jj][2], sacc[jj][3]);
        int byte = lr * 128 + (jj * 16 + lg * 4) * 2;
        byte ^= ((lr & 7) << 4);
        *reinterpret_cast<uint2*>(plb + byte) = pk;
      }
      asm volatile("s_waitcnt lgkmcnt(0)" ::: "memory");
      __builtin_amdgcn_sched_barrier(0);
      // PV for this quarter
      #pragma unroll
      for (int kq = 0; kq < 2; ++kq) {
        int pbyte = lr * 128 + (kq * 64 + lg * 16);
        pbyte ^= ((lr & 7) << 4);
        bf16x8 pf = *reinterpret_cast<const bf16x8*>(plb + pbyte);
        #pragma unroll
        for (int cht = 0; cht < 2; ++cht) {
          const int ch = h * 32 + cht * 16 + lr;
          int vbyte = ch * 512 + (qr * 128 + kq * 64 + lg * 16);
          vbyte ^= ((ch & 7) << 4);
          bf16x8 vf = *reinterpret_cast<const bf16x8*>(vtb + vbyte);
          oacc[cht] = __builtin_amdgcn_mfma_f32_16x16x32_bf16(pf, vf, oacc[cht], 0, 0, 0);
        }
      }
    }

    // row-sum across the 4 lane-groups sharing a row
    psum += __shfl_xor(psum, 16);
    psum += __shfl_xor(psum, 32);
    const float rl = 1.0f / psum;

    // gate (from regs) + deferred normalize -> packed og registers
    #pragma unroll
    for (int cht = 0; cht < 2; ++cht)
      #pragma unroll
      for (int rp = 0; rp < 2; ++rp) {
        const float g0 = bf2f((unsigned short)(gpk[it][cht][rp] & 0xffffu));
        const float g1 = bf2f((unsigned short)(gpk[it][cht][rp] >> 16));
        ogpk[it][cht * 2 + rp] = cvtpk(oacc[cht][rp * 2 + 0] * rl * g0,
                                       oacc[cht][rp * 2 + 1] * rl * g1);
      }
  }

  // ---- og -> zkl LDS [pos][128ch] (K/V dead); swizzle (pos&15)<<4 ----
  __syncthreads();   // all waves done reading K (zkl) and V (vtl)
  #pragma unroll
  for (int it = 0; it < 8; ++it)
    #pragma unroll
    for (int cht = 0; cht < 2; ++cht)
      #pragma unroll
      for (int r = 0; r < 4; ++r) {
        const int pos = ihalf * 128 + it * 16 + lg * 4 + r;
        const int ch  = h * 32 + cht * 16 + lr;
        int byte = pos * 256 + ch * 2;
        byte ^= ((pos & 15) << 4);
        *reinterpret_cast<unsigned short*>(zkb + byte) =
            (unsigned short)(ogpk[it][cht * 2 + (r >> 1)] >> ((r & 1) * 16));
      }
  __syncthreads();   // og tile visible

  // ---- Phase E (fused K3): out^T = w2^T · og^T, og from LDS ----
  {
    const unsigned short* w2T = wT + 4 * (DZc * DHCc);
    bf16x8 zb[2][4];
    #pragma unroll
    for (int sub = 0; sub < 2; ++sub) {
      const int pos = w8 * 32 + sub * 16 + lr;
      #pragma unroll
      for (int kt = 0; kt < 4; ++kt) {
        int byte = pos * 256 + kt * 64 + lg * 16;
        byte ^= ((pos & 15) << 4);
        zb[sub][kt] = *reinterpret_cast<const bf16x8*>(zkb + byte);
      }
    }
    #pragma unroll
    for (int ct = 0; ct < 8; ++ct) {
      bf16x8 af[4];
      #pragma unroll
      for (int kt = 0; kt < 4; ++kt)
        af[kt] = *reinterpret_cast<const bf16x8*>(
            &w2T[(size_t)(ct * 16 + lr) * 128 + kt * 32 + lg * 8]);
      #pragma unroll
      for (int sub = 0; sub < 2; ++sub) {
        f32x4 acc = (f32x4){0.f, 0.f, 0.f, 0.f};
        #pragma unroll
        for (int kt = 0; kt < 4; ++kt)
          acc = __builtin_amdgcn_mfma_f32_16x16x32_bf16(af[kt], zb[sub][kt], acc, 0, 0, 0);
        const size_t gpos = (size_t)n * 256 + w8 * 32 + sub * 16 + lr;
        #pragma unroll
        for (int r = 0; r < 4; ++r) {
          const int c = ct * 16 + lg * 4 + r;
          out[(size_t)c * NPOSc + gpos] = acc[r] + b2[c];
        }
      }
    }
  }
}

// ---------------------------------------------------------------------------
extern "C" void kernel_launch(void* const* d_in, const int* in_sizes, int n_in,
                              void* d_out, int out_size, void* d_ws, size_t ws_size,
                              hipStream_t stream) {
  const float* z   = (const float*)d_in[0];
  const float* lnw = (const float*)d_in[1];
  const float* lnb = (const float*)d_in[2];
  const float* wq  = (const float*)d_in[3];
  const float* bq  = (const float*)d_in[4];
  const float* wk  = (const float*)d_in[5];
  const float* bk  = (const float*)d_in[6];
  const float* wv  = (const float*)d_in[7];
  const float* bv  = (const float*)d_in[8];
  const float* wg  = (const float*)d_in[9];
  const float* bg  = (const float*)d_in[10];
  const float* w2  = (const float*)d_in[11];
  const float* b2  = (const float*)d_in[12];
  float* out = (float*)d_out;

  unsigned short* wT = (unsigned short*)d_ws;   // 5 x 16384 bf16 weights

  prep_weights<<<5, 256, 0, stream>>>(wq, wk, wv, wg, w2, wT);
  fused_ln_proj_attn<<<Lc, 512, 0, stream>>>(
      z, lnw, lnb, wT, bq, bk, bv, bg, b2, out);
}